// Round 3
// baseline (9255.820 us; speedup 1.0000x reference)
//
#include <hip/hip_runtime.h>
#include <hip/hip_bf16.h>
#include <cstddef>

typedef __hip_bfloat16 bf16;

#define T_ 64
#define N_ 1024
#define L_ 16
#define H_ 256
#define HC_ 257
#define G3 771      // 3*HC
#define STATE_ 290

__device__ __forceinline__ float ldf(const float* p){ return *p; }
__device__ __forceinline__ float ldf(const bf16* p){ return __bfloat162float(*p); }
__device__ __forceinline__ void stf(float* p, float v){ *p = v; }
__device__ __forceinline__ void stf(bf16* p, float v){ *p = __float2bfloat16(v); }

// out[r,m] = act(sum_k A[r,k]*W[m,k] + bias[m]); A row-major [R,lda], W row-major [Mo,ldw]
template<typename TA, typename TO, bool RELU>
__global__ __launch_bounds__(256) void gemm_nt(
    const TA* __restrict__ A, int lda,
    const float* __restrict__ W, int ldw,
    const float* __restrict__ bias,
    TO* __restrict__ out, int ldo,
    int R, int Mo, int Kd)
{
  __shared__ float As[16][65];
  __shared__ float Ws[16][65];
  int tx = threadIdx.x & 15, ty = threadIdx.x >> 4;
  int br = blockIdx.x * 64, bm = blockIdx.y * 64;
  float acc[4][4] = {};
  for (int k0 = 0; k0 < Kd; k0 += 16) {
    #pragma unroll
    for (int i = threadIdx.x; i < 1024; i += 256) {
      int rr = i >> 4, kk = i & 15;
      int r = br + rr, k = k0 + kk;
      As[kk][rr] = (r < R && k < Kd) ? ldf(&A[(size_t)r*lda + k]) : 0.f;
      int m = bm + rr;
      Ws[kk][rr] = (m < Mo && k < Kd) ? W[(size_t)m*ldw + k] : 0.f;
    }
    __syncthreads();
    #pragma unroll
    for (int kk = 0; kk < 16; ++kk) {
      float av[4], wv[4];
      #pragma unroll
      for (int i = 0; i < 4; ++i) av[i] = As[kk][ty + 16*i];
      #pragma unroll
      for (int j = 0; j < 4; ++j) wv[j] = Ws[kk][tx + 16*j];
      #pragma unroll
      for (int i = 0; i < 4; ++i)
        #pragma unroll
        for (int j = 0; j < 4; ++j) acc[i][j] += av[i]*wv[j];
    }
    __syncthreads();
  }
  #pragma unroll
  for (int i = 0; i < 4; ++i) {
    int r = br + ty + 16*i;
    if (r >= R) continue;
    #pragma unroll
    for (int j = 0; j < 4; ++j) {
      int m = bm + tx + 16*j;
      if (m >= Mo) continue;
      float v = acc[i][j] + (bias ? bias[m] : 0.f);
      if (RELU) v = fmaxf(v, 0.f);
      stf(&out[(size_t)r*ldo + m], v);
    }
  }
}

// GRU gate combine for encoder (HC=257). gi row = row mod N (broadcast over i for fwd).
template<typename TG>
__global__ void gru_gate_enc(const float* __restrict__ gi, const TG* __restrict__ gh,
                             const float* __restrict__ hprev, float* __restrict__ hout, int rows)
{
  int idx = blockIdx.x*256 + threadIdx.x;
  int row = idx / HC_, c = idx - row*HC_;
  if (row >= rows) return;
  int n = row & (N_-1);
  const float* gir = gi + (size_t)n*G3;
  const TG* ghr = gh + (size_t)row*G3;
  float hp = hprev ? hprev[(size_t)row*HC_ + c] : 0.f;
  float r = 1.f/(1.f + expf(-(gir[c] + ldf(&ghr[c]))));
  float z = 1.f/(1.f + expf(-(gir[HC_+c] + ldf(&ghr[HC_+c]))));
  float g = tanhf(gir[2*HC_+c] + r*ldf(&ghr[2*HC_+c]));
  hout[(size_t)row*HC_ + c] = (1.f - z)*g + z*hp;
}

__global__ void embed_kernel(const int* __restrict__ lines, const float* __restrict__ emb,
                             float* __restrict__ M)
{
  size_t idx = (size_t)blockIdx.x*256 + threadIdx.x;
  if (idx >= (size_t)N_*L_*H_) return;
  int hcol = idx & (H_-1);
  size_t nl = idx >> 8;
  int tok = lines[nl];
  M[idx] = emb[(size_t)tok*H_ + hcol];
}

__global__ void init_state(const float* __restrict__ hxs, float* __restrict__ h,
                           float* __restrict__ p0)
{
  int n = blockIdx.x, t = threadIdx.x;
  __shared__ int nz;
  if (t == 0) nz = 0;
  __syncthreads();
  for (int c = t; c < STATE_; c += 256)
    if (hxs[(size_t)n*STATE_ + c] != 0.f) atomicOr(&nz, 1);
  __syncthreads();
  bool new_ep = (nz == 0);
  for (int c = t; c < H_; c += 256) h[(size_t)n*H_ + c] = hxs[(size_t)n*STATE_ + 2 + c];
  if (t < L_) {
    float pv = hxs[(size_t)n*STATE_ + 2 + H_ + L_ + t];
    if (t == 0 && new_ep) pv = 1.f;
    p0[n*L_ + t] = pv;
  }
}

__global__ void r0_kernel(const float* __restrict__ p0, const float* __restrict__ M,
                          float* __restrict__ r0)
{
  int n = blockIdx.x, c = threadIdx.x;
  float s = 0.f;
  for (int l = 0; l < L_; ++l) s += p0[n*L_ + l]*M[((size_t)n*L_ + l)*H_ + c];
  r0[(size_t)n*H_ + c] = s;
}

__global__ void transpose256(const float* __restrict__ Wa, float* __restrict__ WaT)
{
  int m = blockIdx.x, k = threadIdx.x;
  WaT[(size_t)m*H_ + k] = Wa[(size_t)k*H_ + m];   // WaT[m][h'] = Wa[h'][m]
}

// after fwd step j: K[n,j,:] = sum_{i<=j} F[i,n,:256]; C[n,i,j] = F[i,n,256] for i<=j
__global__ void accum_fwd(const float* __restrict__ F, float* __restrict__ Km,
                          float* __restrict__ Cm, int j)
{
  int n = blockIdx.x, c = threadIdx.x;
  float s = 0.f;
  for (int i = 0; i <= j; ++i) s += F[((size_t)i*N_ + n)*HC_ + c];
  Km[((size_t)n*L_ + j)*H_ + c] = s;
  if (c <= j) Cm[((size_t)n*L_ + c)*L_ + j] = F[((size_t)c*N_ + n)*HC_ + H_];
}

// B part: K[n,j,:] += sum_{k<=14-j} B[k,n,:256]; C[n,i,j] = B[i-1-j,n,256] for i>j
__global__ void accum_bwd(const float* __restrict__ Bm, float* __restrict__ Km,
                          float* __restrict__ Cm)
{
  int n = blockIdx.x, c = threadIdx.x;
  float s = 0.f;
  for (int jj = 15; jj >= 0; --jj) {
    if (jj < 15) s += Bm[((size_t)(14-jj)*N_ + n)*HC_ + c];
    Km[((size_t)n*L_ + jj)*H_ + c] += s;
  }
  int i = c >> 4, j = c & 15;
  if (i > j) Cm[((size_t)n*L_ + i)*L_ + j] = Bm[((size_t)(i-1-j)*N_ + n)*HC_ + H_];
}

__global__ void wb_kernel(const float* __restrict__ Km, const float* __restrict__ ba,
                          float* __restrict__ wbv)
{
  int n = blockIdx.x, t = threadIdx.x;
  int l = t >> 4, lane = t & 15;
  float s = 0.f;
  for (int m = lane; m < H_; m += 16) s += Km[((size_t)n*L_ + l)*H_ + m]*ba[m];
  s += __shfl_down(s, 8, 16); s += __shfl_down(s, 4, 16);
  s += __shfl_down(s, 2, 16); s += __shfl_down(s, 1, 16);
  if (lane == 0) wbv[n*L_ + l] = s;
}

__global__ void build_xcat(const float* __restrict__ cond, const int* __restrict__ act,
                           const float* __restrict__ r0v, const float* __restrict__ M,
                           bf16* __restrict__ xcat)
{
  size_t idx = (size_t)blockIdx.x*256 + threadIdx.x;
  if (idx >= (size_t)T_*N_*320) return;
  int k = (int)(idx % 320);
  size_t row = idx / 320;
  int n = (int)(row & (N_-1)), t = (int)(row >> 10);
  float v;
  if (k < 64) v = cond[row*64 + k];
  else {
    int c = k - 64;
    if (t == 0) v = r0v[(size_t)n*H_ + c];
    else { int a = act[(size_t)(t-1)*N_ + n]; v = M[((size_t)n*L_ + a)*H_ + c]; }
  }
  xcat[idx] = __float2bfloat16(v);
}

__global__ __launch_bounds__(256) void step_kernel(
    int t, const float* __restrict__ ggi, const float* __restrict__ ggh,
    float* __restrict__ h, const float* __restrict__ Ktl,
    const float* __restrict__ wbv, const float* __restrict__ Cm,
    const float* __restrict__ p0, const int* __restrict__ act,
    const float* __restrict__ Wc, const float* __restrict__ bc,
    float* __restrict__ out)
{
  int n = blockIdx.x, c = threadIdx.x;
  __shared__ float sh[256];
  __shared__ float psh[16];
  __shared__ float vred[4];
  __shared__ float sden;
  const float* gi = ggi + (size_t)n*768;
  const float* gh = ggh + (size_t)n*768;
  float hp = h[(size_t)n*H_ + c];
  float r = 1.f/(1.f + expf(-(gi[c] + gh[c])));
  float z = 1.f/(1.f + expf(-(gi[256+c] + gh[256+c])));
  float g = tanhf(gi[512+c] + r*gh[512+c]);
  float h2 = (1.f - z)*g + z*hp;
  h[(size_t)n*H_ + c] = h2;
  sh[c] = h2;
  float pv = h2 * Wc[c];
  #pragma unroll
  for (int off = 32; off > 0; off >>= 1) pv += __shfl_down(pv, off, 64);
  if ((c & 63) == 0) vred[c >> 6] = pv;
  __syncthreads();
  int l = c >> 4, lane = c & 15;
  const float* Kt = Ktl + ((size_t)n*L_ + l)*H_;
  float s = 0.f;
  #pragma unroll
  for (int m = lane; m < H_; m += 16) s += Kt[m]*sh[m];
  s += __shfl_down(s, 8, 16); s += __shfl_down(s, 4, 16);
  s += __shfl_down(s, 2, 16); s += __shfl_down(s, 1, 16);
  if (lane == 0) {
    float catt;
    if (t == 0) {
      catt = 0.f;
      for (int i = 0; i < L_; ++i) catt += p0[n*L_ + i]*Cm[((size_t)n*L_ + i)*L_ + l];
    } else {
      int ap = act[(size_t)(t-1)*N_ + n];
      catt = Cm[((size_t)n*L_ + ap)*L_ + l];
    }
    psh[l] = (s + wbv[n*L_ + l]) * catt;
  }
  __syncthreads();
  if (c == 0) {
    float mx = psh[0];
    for (int i = 1; i < L_; ++i) mx = fmaxf(mx, psh[i]);
    float ss = 0.f;
    for (int i = 0; i < L_; ++i) { psh[i] = expf(psh[i] - mx); ss += psh[i]; }
    sden = ss;
  }
  __syncthreads();
  int a = act[(size_t)t*N_ + n];
  float vv = vred[0] + vred[1] + vred[2] + vred[3] + bc[0];
  size_t ob = ((size_t)t*N_ + n)*STATE_;
  out[ob + 2 + c] = h2;
  if (c == 0) { out[ob] = (float)a; out[ob + 1] = vv; }
  if (c < L_) {
    out[ob + 258 + c] = psh[c]/sden;
    out[ob + 274 + c] = (c == a ? 1.f : 0.f);
  }
  if (t == T_-1) {
    size_t ob2 = ((size_t)T_*N_ + n)*STATE_;
    out[ob2 + 2 + c] = h2;
    if (c == 0) { out[ob2] = (float)a; out[ob2 + 1] = vv; }
    if (c < L_) {
      out[ob2 + 258 + c] = psh[c]/sden;
      out[ob2 + 274 + c] = (c == a ? 1.f : 0.f);
    }
  }
}

extern "C" void kernel_launch(void* const* d_in, const int* in_sizes, int n_in,
                              void* d_out, int out_size, void* d_ws, size_t ws_size,
                              hipStream_t stream)
{
  const float* cond  = (const float*)d_in[0];
  const int*   lines = (const int*)  d_in[1];
  const int*   act   = (const int*)  d_in[2];
  const float* hxs   = (const float*)d_in[3];
  const float* emb   = (const float*)d_in[4];
  const float* wih_e = (const float*)d_in[5];
  const float* whh_e = (const float*)d_in[6];
  const float* bih_e = (const float*)d_in[7];
  const float* bhh_e = (const float*)d_in[8];
  const float* W1    = (const float*)d_in[9];
  const float* b1    = (const float*)d_in[10];
  const float* W2    = (const float*)d_in[11];
  const float* b2    = (const float*)d_in[12];
  const float* wih_c = (const float*)d_in[13];
  const float* whh_c = (const float*)d_in[14];
  const float* bih_c = (const float*)d_in[15];
  const float* bhh_c = (const float*)d_in[16];
  const float* Wa    = (const float*)d_in[17];
  const float* ba    = (const float*)d_in[18];
  const float* Wc    = (const float*)d_in[19];
  const float* bc    = (const float*)d_in[20];
  float* out = (float*)d_out;   // reference output dtype is float32

  // ---- workspace layout with lifetime overlays (total ~121 MB) ----
  char* base = (char*)d_ws;
  float* M    = (float*)(base + 0);           // [N,L,H] f32, phases 1-4
  float* Bm   = (float*)(base + 16777216);    // [L,N,HC] f32, phase 1
  float* F    = (float*)(base + 33619968);    // [L,N,HC] f32, phase 1
  float* Km   = (float*)(base + 50462720);    // [N,L,H] f32, phases 1-2
  float* Ktl  = (float*)(base + 67239936);    // [N,L,H] f32, phases 2-4
  bf16*  gef  = (bf16*) (base + 84017152);    // [L,N,G3] bf16, phase 1
  float* gei  = (float*)(base + 109281280);   // [N,G3] f32, phase 1
  float* zb   = (float*)(base + 112439296);   // [N,HC] f32 zeros, phase 1
  bf16*  xcat = (bf16*) (base + 16777216);    // [T,N,320] bf16, phase 3 (over Bm/F/Km-head)
  bf16*  x1   = (bf16*) (base + 84017152);    // [T,N,H] bf16, phase 3 (over gef/gei/zb)
  bf16*  x2   = (bf16*) (base + 16777216);    // [T,N,H] bf16, phases 3-4 (over xcat)
  float* ggi  = (float*)(base + 58720256);    // [N,768] f32, phase 4 (over Km tail)
  float* ggh  = (float*)(base + 61865984);    // [N,768] f32, phase 4 (over Km tail)
  float* Cm   = (float*)(base + 117571584);   // [N,L,L] f32
  float* hbuf = (float*)(base + 118620160);   // [N,H] f32
  float* p0   = (float*)(base + 119668736);   // [N,L] f32
  float* r0v  = (float*)(base + 119734272);   // [N,H] f32
  float* wbv  = (float*)(base + 120782848);   // [N,L] f32
  float* WaT  = (float*)(base + 120848384);   // [H,H] f32   (ends 121,110,528)

  hipMemsetAsync(F, 0, (size_t)L_*N_*HC_*sizeof(float), stream);
  hipMemsetAsync(zb, 0, (size_t)N_*HC_*sizeof(float), stream);

  embed_kernel<<<(N_*L_*H_ + 255)/256, 256, 0, stream>>>(lines, emb, M);
  init_state<<<N_, 256, 0, stream>>>(hxs, hbuf, p0);
  r0_kernel<<<N_, 256, 0, stream>>>(p0, M, r0v);
  transpose256<<<256, 256, 0, stream>>>(Wa, WaT);

  dim3 blk(256);
  dim3 gEnc((N_ + 63)/64, (G3 + 63)/64);

  // phase 1a: backward encoder scan (B[k] = enc of reversed prefix)
  for (int k = 0; k < L_; ++k) {
    int lpos = L_ - 1 - k;
    gemm_nt<float,float,false><<<gEnc, blk, 0, stream>>>(M + lpos*H_, L_*H_, wih_e, H_, bih_e, gei, G3, N_, G3, H_);
    const float* hp = k ? Bm + (size_t)(k-1)*N_*HC_ : zb;
    gemm_nt<float,bf16,false><<<gEnc, blk, 0, stream>>>(hp, HC_, whh_e, HC_, bhh_e, gef, G3, N_, G3, HC_);
    gru_gate_enc<bf16><<<(N_*HC_ + 255)/256, 256, 0, stream>>>(gei, gef, k ? Bm + (size_t)(k-1)*N_*HC_ : nullptr,
                                                               Bm + (size_t)k*N_*HC_, N_);
  }
  // phase 1b: forward encoder (triangular; only i<=j rows evolve); accumulate K/C on the fly
  for (int j = 0; j < L_; ++j) {
    gemm_nt<float,float,false><<<gEnc, blk, 0, stream>>>(M + j*H_, L_*H_, wih_e, H_, bih_e, gei, G3, N_, G3, H_);
    int rows = (j+1)*N_;
    dim3 g2((rows + 63)/64, (G3 + 63)/64);
    gemm_nt<float,bf16,false><<<g2, blk, 0, stream>>>(F, HC_, whh_e, HC_, bhh_e, gef, G3, rows, G3, HC_);
    gru_gate_enc<bf16><<<(rows*HC_ + 255)/256, 256, 0, stream>>>(gei, gef, F, F, rows);
    accum_fwd<<<N_, 256, 0, stream>>>(F, Km, Cm, j);
  }
  accum_bwd<<<N_, 256, 0, stream>>>(Bm, Km, Cm);

  // phase 2: fold Wa/ba into K
  {
    dim3 g3((N_*L_ + 63)/64, (H_ + 63)/64);
    gemm_nt<float,float,false><<<g3, blk, 0, stream>>>(Km, H_, WaT, H_, nullptr, Ktl, H_, N_*L_, H_, H_);
  }
  wb_kernel<<<N_, 256, 0, stream>>>(Km, ba, wbv);

  // phase 3: batched MLP over all T
  build_xcat<<<(int)(((size_t)T_*N_*320 + 255)/256), 256, 0, stream>>>(cond, act, r0v, M, xcat);
  {
    dim3 g4((T_*N_ + 63)/64, (H_ + 63)/64);
    gemm_nt<bf16,bf16,true><<<g4, blk, 0, stream>>>(xcat, 320, W1, 320, b1, x1, H_, T_*N_, H_, 320);
    gemm_nt<bf16,bf16,true><<<g4, blk, 0, stream>>>(x1, H_, W2, H_, b2, x2, H_, T_*N_, H_, H_);
  }

  // phase 4: sequential T loop (only gh depends on h)
  dim3 g5((N_ + 63)/64, (768 + 63)/64);
  for (int t = 0; t < T_; ++t) {
    gemm_nt<bf16,float,false><<<g5, blk, 0, stream>>>(x2 + (size_t)t*N_*H_, H_, wih_c, H_, bih_c, ggi, 768, N_, 768, H_);
    gemm_nt<float,float,false><<<g5, blk, 0, stream>>>(hbuf, H_, whh_c, H_, bhh_c, ggh, 768, N_, 768, H_);
    step_kernel<<<N_, 256, 0, stream>>>(t, ggi, ggh, hbuf, Ktl, wbv, Cm, p0, act, Wc, bc, out);
  }
}

// Round 4
// 8595.432 us; speedup vs baseline: 1.0768x; 1.0768x over previous
//
#include <hip/hip_runtime.h>
#include <hip/hip_bf16.h>
#include <cstddef>

#define T_ 64
#define N_ 1024
#define L_ 16
#define H_ 256
#define STATE_ 290

typedef short s16x8 __attribute__((ext_vector_type(8)));
typedef float f32x4 __attribute__((ext_vector_type(4)));
#define MFMA16 __builtin_amdgcn_mfma_f32_16x16x32_bf16

__device__ __forceinline__ float b2f(ushort u){ return __uint_as_float(((unsigned)u) << 16); }
__device__ __forceinline__ ushort f2b(float f){
  unsigned x = __float_as_uint(f);
  return (ushort)((x + 0x7FFFu + ((x >> 16) & 1u)) >> 16);
}
__device__ __forceinline__ float gruh(float gir,float giz,float gig,
                                      float ghr,float ghz,float ghg,float hp){
  float r = 1.f/(1.f + __expf(-(gir + ghr)));
  float z = 1.f/(1.f + __expf(-(giz + ghz)));
  float g = tanhf(gig + r*ghg);
  return (1.f - z)*g + z*hp;
}

// ---------- conversion / prep kernels ----------
__global__ void conv_pad_b(const float* __restrict__ src, ushort* __restrict__ dst,
                           int R, int C, int Cp, int total){
  int idx = blockIdx.x*256 + threadIdx.x;
  if (idx >= total) return;
  int r = idx / Cp, c = idx - r*Cp;
  dst[idx] = (r < R && c < C) ? f2b(src[(size_t)r*C + c]) : (ushort)0;
}
// encoder weights [771, Ci] -> permuted [832, Cp]; dst row d=(3k+p)*16+u <- src row p*257+16k+u
__global__ void perm_enc_w(const float* __restrict__ src, ushort* __restrict__ dst,
                           int Ci, int Cp, int total){
  int idx = blockIdx.x*256 + threadIdx.x;
  if (idx >= total) return;
  int d = idx / Cp, c = idx - d*Cp;
  int tile = d >> 4, u = d & 15;
  int k = tile / 3, p = tile - 3*k;
  int hc = k*16 + u;
  bool ok = (tile < 51) && (hc < 257) && (c < Ci);
  dst[idx] = ok ? f2b(src[(size_t)(p*257 + hc)*Ci + c]) : (ushort)0;
}
// cell weights [768,256] -> permuted [768,256]; dst row (3k+p)*16+u <- src row p*256+16k+u
__global__ void perm_cell_w(const float* __restrict__ src, ushort* __restrict__ dst){
  int idx = blockIdx.x*256 + threadIdx.x;
  if (idx >= 768*256) return;
  int d = idx >> 8, c = idx & 255;
  int tile = d >> 4, u = d & 15;
  int k = tile / 3, p = tile - 3*k;
  dst[idx] = f2b(src[(size_t)(p*256 + k*16 + u)*256 + c]);
}
__global__ void transp_b(const float* __restrict__ Wa, ushort* __restrict__ WaTb){
  int m = blockIdx.x, h = threadIdx.x;
  WaTb[(size_t)h*256 + m] = f2b(Wa[(size_t)m*256 + h]);
}
__global__ void embed_b(const int* __restrict__ lines, const float* __restrict__ emb,
                        ushort* __restrict__ Mbf){
  size_t idx = (size_t)blockIdx.x*256 + threadIdx.x;
  if (idx >= (size_t)N_*L_*H_) return;
  int c = idx & 255; size_t nl = idx >> 8;
  Mbf[idx] = f2b(emb[(size_t)lines[nl]*256 + c]);
}
__global__ void init_state(const float* __restrict__ hxs, float* __restrict__ hbuf,
                           float* __restrict__ p0){
  int n = blockIdx.x, t = threadIdx.x;
  __shared__ int nz;
  if (t == 0) nz = 0;
  __syncthreads();
  for (int c = t; c < STATE_; c += 256)
    if (hxs[(size_t)n*STATE_ + c] != 0.f) atomicOr(&nz, 1);
  __syncthreads();
  bool new_ep = (nz == 0);
  for (int c = t; c < H_; c += 256) hbuf[(size_t)n*H_ + c] = hxs[(size_t)n*STATE_ + 2 + c];
  if (t < L_) {
    float pv = hxs[(size_t)n*STATE_ + 2 + H_ + L_ + t];
    if (t == 0 && new_ep) pv = 1.f;
    p0[n*L_ + t] = pv;
  }
}
__global__ void r0_kernel(const float* __restrict__ p0, const ushort* __restrict__ Mbf,
                          float* __restrict__ r0v){
  int n = blockIdx.x, c = threadIdx.x;
  float s = 0.f;
  for (int l = 0; l < 16; ++l) s += p0[n*16 + l]*b2f(Mbf[((size_t)n*16 + l)*256 + c]);
  r0v[(size_t)n*256 + c] = s;
}
__global__ void km2bf(const float* __restrict__ Km, ushort* __restrict__ Kmbf){
  size_t idx = (size_t)blockIdx.x*256 + threadIdx.x;
  if (idx < (size_t)16384*256) Kmbf[idx] = f2b(Km[idx]);
}
__global__ void build_xcat(const float* __restrict__ cond, const int* __restrict__ act,
                           const float* __restrict__ r0v, const ushort* __restrict__ Mbf,
                           ushort* __restrict__ xcat){
  size_t idx = (size_t)blockIdx.x*256 + threadIdx.x;
  if (idx >= (size_t)T_*N_*320) return;
  int k = (int)(idx % 320);
  size_t row = idx / 320;
  int n = (int)(row & 1023), t = (int)(row >> 10);
  ushort v;
  if (k < 64) v = f2b(cond[row*64 + k]);
  else {
    int c = k - 64;
    if (t == 0) v = f2b(r0v[(size_t)n*256 + c]);
    else { int a = act[(size_t)(t-1)*1024 + n]; v = Mbf[((size_t)n*16 + a)*256 + c]; }
  }
  xcat[idx] = v;
}

// ---------- MFMA GEMM: out[r,col] = act(sum_k A[r,k]*W[col,k] + bias[col]), bf16 out ----------
template<int RELU>
__global__ __launch_bounds__(256) void gemm_mfma(
    const ushort* __restrict__ A, const ushort* __restrict__ W,
    const float* __restrict__ bias, ushort* __restrict__ out,
    int Kd, int ldo){
  int lane = threadIdx.x & 63, wv = threadIdx.x >> 6;
  int u = lane & 15, g4 = lane >> 4;
  int br = blockIdx.x*64 + wv*16;
  int bm = blockIdx.y*64;
  const ushort* Arow = A + (size_t)(br + u)*Kd + g4*8;
  f32x4 acc0 = {0,0,0,0}, acc1 = {0,0,0,0}, acc2 = {0,0,0,0}, acc3 = {0,0,0,0};
  for (int k0 = 0; k0 < Kd; k0 += 32) {
    s16x8 av = *(const s16x8*)(Arow + k0);
    s16x8 b0 = *(const s16x8*)(W + (size_t)(bm +  0 + u)*Kd + k0 + g4*8);
    s16x8 b1 = *(const s16x8*)(W + (size_t)(bm + 16 + u)*Kd + k0 + g4*8);
    s16x8 b2 = *(const s16x8*)(W + (size_t)(bm + 32 + u)*Kd + k0 + g4*8);
    s16x8 b3 = *(const s16x8*)(W + (size_t)(bm + 48 + u)*Kd + k0 + g4*8);
    acc0 = MFMA16(av, b0, acc0, 0,0,0);
    acc1 = MFMA16(av, b1, acc1, 0,0,0);
    acc2 = MFMA16(av, b2, acc2, 0,0,0);
    acc3 = MFMA16(av, b3, acc3, 0,0,0);
  }
  f32x4 ac[4] = {acc0, acc1, acc2, acc3};
  #pragma unroll
  for (int mt = 0; mt < 4; ++mt) {
    int col = bm + mt*16 + u;
    float b = bias ? bias[col] : 0.f;
    #pragma unroll
    for (int r = 0; r < 4; ++r) {
      float v = ac[mt][r] + b;
      if (RELU) v = fmaxf(v, 0.f);
      out[(size_t)(br + g4*4 + r)*ldo + col] = f2b(v);
    }
  }
}

// ---------- backward encoder scan: one launch, 64 blocks x 16 n's, 16 steps ----------
__global__ __launch_bounds__(256) void enc1a(
    const ushort* __restrict__ GiAll, const ushort* __restrict__ Wh,
    const float* __restrict__ bih, const float* __restrict__ bhh,
    ushort* __restrict__ Bbf){
  __shared__ __align__(16) ushort hbf[16][328];
  int tid = threadIdx.x, lane = tid & 63, wv = tid >> 6;
  int u = lane & 15, g4 = lane >> 4;
  int n0 = blockIdx.x * 16;
  for (int i = tid; i < 16*328; i += 256) ((ushort*)hbf)[i] = 0;
  __syncthreads();
  int kb = wv ? (1 + wv*4) : 0;
  int cnt = wv ? 4 : 5;
  for (int step = 0; step < 16; ++step) {
    int l = 15 - step;
    s16x8 AH[9];
    #pragma unroll
    for (int q = 0; q < 9; ++q) AH[q] = *(const s16x8*)&hbf[u][q*32 + g4*8];
    float h2s[5][4];
    #pragma unroll
    for (int ktl = 0; ktl < 5; ++ktl) {
      if (ktl >= cnt) continue;
      int kt = kb + ktl;
      f32x4 a0 = {0,0,0,0}, a1 = {0,0,0,0}, a2 = {0,0,0,0};
      #pragma unroll
      for (int q = 0; q < 9; ++q) {
        int k0 = q*32;
        s16x8 b0 = *(const s16x8*)(Wh + (size_t)((3*kt+0)*16 + u)*288 + k0 + g4*8);
        s16x8 b1 = *(const s16x8*)(Wh + (size_t)((3*kt+1)*16 + u)*288 + k0 + g4*8);
        s16x8 b2 = *(const s16x8*)(Wh + (size_t)((3*kt+2)*16 + u)*288 + k0 + g4*8);
        a0 = MFMA16(AH[q], b0, a0, 0,0,0);
        a1 = MFMA16(AH[q], b1, a1, 0,0,0);
        a2 = MFMA16(AH[q], b2, a2, 0,0,0);
      }
      int c = kt*16 + u;
      bool cv = (c < 257);
      #pragma unroll
      for (int r = 0; r < 4; ++r) {
        int row = g4*4 + r;
        float hp = b2f(hbf[row][cv ? c : 0]);
        float h2 = hp;
        if (cv) {
          const ushort* gi = GiAll + ((size_t)(n0+row)*16 + l)*832 + 3*kt*16 + u;
          h2 = gruh(b2f(gi[0]) + bih[c], b2f(gi[16]) + bih[257+c], b2f(gi[32]) + bih[514+c],
                    a0[r] + bhh[c], a1[r] + bhh[257+c], a2[r] + bhh[514+c], hp);
          Bbf[((size_t)step*1024 + n0 + row)*288 + c] = f2b(h2);
        }
        h2s[ktl][r] = h2;
      }
    }
    __syncthreads();
    #pragma unroll
    for (int ktl = 0; ktl < 5; ++ktl) {
      if (ktl >= cnt) continue;
      int c = (kb+ktl)*16 + u;
      if (c < 257) {
        #pragma unroll
        for (int r = 0; r < 4; ++r) hbf[g4*4 + r][c] = f2b(h2s[ktl][r]);
      }
    }
    __syncthreads();
  }
}

// ---------- forward triangular encoder: 256 blocks x (4 n x 16 i) rows, 16 steps ----------
__global__ __launch_bounds__(256) void enc1b(
    const ushort* __restrict__ GiAll, const ushort* __restrict__ Wh,
    const float* __restrict__ bih, const float* __restrict__ bhh,
    float* __restrict__ Km, float* __restrict__ Cm){
  __shared__ __align__(16) ushort hbf[64][328];
  int tid = threadIdx.x, lane = tid & 63, wv = tid >> 6;
  int u = lane & 15, g4 = lane >> 4;
  int nb = blockIdx.x * 4;                 // 4 batch rows; in-block row = i*4 + nl
  for (int i = tid; i < 64*328; i += 256) ((ushort*)hbf)[i] = 0;
  __syncthreads();
  int kb = wv ? (1 + wv*4) : 0;
  int cnt = wv ? 4 : 5;
  for (int j = 0; j < 16; ++j) {
    unsigned h2p[5][4][2];
    #pragma unroll
    for (int ktl = 0; ktl < 5; ++ktl) {
      if (ktl >= cnt) continue;
      int kt = kb + ktl;
      f32x4 acc[4][3];
      #pragma unroll
      for (int rt = 0; rt < 4; ++rt) { acc[rt][0] = {0,0,0,0}; acc[rt][1] = {0,0,0,0}; acc[rt][2] = {0,0,0,0}; }
      #pragma unroll
      for (int q = 0; q < 9; ++q) {
        int k0 = q*32;
        s16x8 b0 = *(const s16x8*)(Wh + (size_t)((3*kt+0)*16 + u)*288 + k0 + g4*8);
        s16x8 b1 = *(const s16x8*)(Wh + (size_t)((3*kt+1)*16 + u)*288 + k0 + g4*8);
        s16x8 b2 = *(const s16x8*)(Wh + (size_t)((3*kt+2)*16 + u)*288 + k0 + g4*8);
        #pragma unroll
        for (int rt = 0; rt < 4; ++rt) {
          if (rt*4 > j) continue;  // whole row-tile inactive
          s16x8 av = *(const s16x8*)&hbf[rt*16 + u][k0 + g4*8];
          acc[rt][0] = MFMA16(av, b0, acc[rt][0], 0,0,0);
          acc[rt][1] = MFMA16(av, b1, acc[rt][1], 0,0,0);
          acc[rt][2] = MFMA16(av, b2, acc[rt][2], 0,0,0);
        }
      }
      int c = kt*16 + u;
      bool cv = (c < 257);
      float kmP[4] = {0.f, 0.f, 0.f, 0.f};
      #pragma unroll
      for (int rt = 0; rt < 4; ++rt) {
        int ii = rt*4 + g4;
        bool act = cv && (ii <= j);
        float h2v[4];
        #pragma unroll
        for (int r = 0; r < 4; ++r) {
          int rowl = rt*16 + g4*4 + r;
          float hp = b2f(hbf[rowl][cv ? c : 0]);
          if (act) {
            const ushort* gi = GiAll + ((size_t)(nb+r)*16 + j)*832 + 3*kt*16 + u;
            h2v[r] = gruh(b2f(gi[0]) + bih[c], b2f(gi[16]) + bih[257+c], b2f(gi[32]) + bih[514+c],
                          acc[rt][0][r] + bhh[c], acc[rt][1][r] + bhh[257+c], acc[rt][2][r] + bhh[514+c], hp);
            if (c < 256) kmP[r] += h2v[r];
            if (c == 256) Cm[(size_t)(nb+r)*256 + ii*16 + j] = h2v[r];
          } else h2v[r] = hp;
        }
        h2p[ktl][rt][0] = (unsigned)f2b(h2v[0]) | ((unsigned)f2b(h2v[1]) << 16);
        h2p[ktl][rt][1] = (unsigned)f2b(h2v[2]) | ((unsigned)f2b(h2v[3]) << 16);
      }
      if (kt < 16) {   // Km store (fwd part, full in-block sum over i)
        #pragma unroll
        for (int r = 0; r < 4; ++r) {
          float s = kmP[r];
          s += __shfl_xor(s, 16, 64);
          s += __shfl_xor(s, 32, 64);
          if (lane < 16) Km[((size_t)(nb+r)*16 + j)*256 + c] = s;
        }
      }
    }
    __syncthreads();
    #pragma unroll
    for (int ktl = 0; ktl < 5; ++ktl) {
      if (ktl >= cnt) continue;
      int c = (kb+ktl)*16 + u;
      if (c < 257) {
        #pragma unroll
        for (int rt = 0; rt < 4; ++rt) {
          int ii = rt*4 + g4;
          if (ii <= j) {
            hbf[rt*16 + g4*4 + 0][c] = (ushort)(h2p[ktl][rt][0] & 0xFFFFu);
            hbf[rt*16 + g4*4 + 1][c] = (ushort)(h2p[ktl][rt][0] >> 16);
            hbf[rt*16 + g4*4 + 2][c] = (ushort)(h2p[ktl][rt][1] & 0xFFFFu);
            hbf[rt*16 + g4*4 + 3][c] = (ushort)(h2p[ktl][rt][1] >> 16);
          }
        }
      }
    }
    __syncthreads();
  }
}

// ---------- backward-part K accumulate + C fill (i>j) ----------
__global__ void accum_bwd(const ushort* __restrict__ Bbf, float* __restrict__ Km,
                          float* __restrict__ Cm){
  int n = blockIdx.x, c = threadIdx.x;
  float s = 0.f;
  for (int jj = 15; jj >= 0; --jj) {
    if (jj < 15) s += b2f(Bbf[((size_t)(14-jj)*1024 + n)*288 + c]);
    Km[((size_t)n*16 + jj)*256 + c] += s;
  }
  int i = c >> 4, j = c & 15;
  if (i > j) Cm[(size_t)n*256 + i*16 + j] = b2f(Bbf[((size_t)(i-1-j)*1024 + n)*288 + 256]);
}
__global__ void wb_kernel(const float* __restrict__ Km, const float* __restrict__ ba,
                          float* __restrict__ wbv){
  int n = blockIdx.x, t = threadIdx.x;
  int l = t >> 4, lane = t & 15;
  float s = 0.f;
  for (int m = lane; m < 256; m += 16) s += Km[((size_t)n*16 + l)*256 + m]*ba[m];
  s += __shfl_down(s, 8, 16); s += __shfl_down(s, 4, 16);
  s += __shfl_down(s, 2, 16); s += __shfl_down(s, 1, 16);
  if (lane == 0) wbv[n*16 + l] = s;
}

// ---------- phase 4: whole T-loop in one launch, 64 blocks x 16 n's ----------
__global__ __launch_bounds__(256) void cell_persist(
    const ushort* __restrict__ x2, const ushort* __restrict__ Wi, const ushort* __restrict__ Wh,
    const float* __restrict__ bih, const float* __restrict__ bhh,
    const float* __restrict__ hbuf, const float* __restrict__ p0, const int* __restrict__ act,
    const ushort* __restrict__ Ktl, const float* __restrict__ wbv, const float* __restrict__ Cm,
    const float* __restrict__ Wc, const float* __restrict__ bc, float* __restrict__ out){
  __shared__ __align__(16) ushort hbf[16][264];
  __shared__ float vred[4][16];
  __shared__ float vfin[16];
  int tid = threadIdx.x, lane = tid & 63, wv = tid >> 6;
  int u = lane & 15, g4 = lane >> 4;
  int n0 = blockIdx.x * 16;
  for (int i = tid; i < 16*256; i += 256) {
    int rr = i >> 8, cc = i & 255;
    hbf[rr][cc] = f2b(hbuf[(size_t)(n0 + rr)*256 + cc]);
  }
  __syncthreads();
  int kb = wv*4;
  for (int t = 0; t < 64; ++t) {
    s16x8 ai[8], ah[8];
    #pragma unroll
    for (int q = 0; q < 8; ++q) {
      ai[q] = *(const s16x8*)(x2 + ((size_t)t*1024 + n0 + u)*256 + q*32 + g4*8);
      ah[q] = *(const s16x8*)&hbf[u][q*32 + g4*8];
    }
    float h2s[4][4];
    float vp[4] = {0.f, 0.f, 0.f, 0.f};
    #pragma unroll
    for (int ktl = 0; ktl < 4; ++ktl) {
      int kt = kb + ktl;
      f32x4 gi0 = {0,0,0,0}, gi1 = {0,0,0,0}, gi2 = {0,0,0,0};
      f32x4 gh0 = {0,0,0,0}, gh1 = {0,0,0,0}, gh2 = {0,0,0,0};
      #pragma unroll
      for (int q = 0; q < 8; ++q) {
        int k0 = q*32;
        s16x8 wi0 = *(const s16x8*)(Wi + (size_t)((3*kt+0)*16 + u)*256 + k0 + g4*8);
        s16x8 wi1 = *(const s16x8*)(Wi + (size_t)((3*kt+1)*16 + u)*256 + k0 + g4*8);
        s16x8 wi2 = *(const s16x8*)(Wi + (size_t)((3*kt+2)*16 + u)*256 + k0 + g4*8);
        s16x8 wh0 = *(const s16x8*)(Wh + (size_t)((3*kt+0)*16 + u)*256 + k0 + g4*8);
        s16x8 wh1 = *(const s16x8*)(Wh + (size_t)((3*kt+1)*16 + u)*256 + k0 + g4*8);
        s16x8 wh2 = *(const s16x8*)(Wh + (size_t)((3*kt+2)*16 + u)*256 + k0 + g4*8);
        gi0 = MFMA16(ai[q], wi0, gi0, 0,0,0);
        gi1 = MFMA16(ai[q], wi1, gi1, 0,0,0);
        gi2 = MFMA16(ai[q], wi2, gi2, 0,0,0);
        gh0 = MFMA16(ah[q], wh0, gh0, 0,0,0);
        gh1 = MFMA16(ah[q], wh1, gh1, 0,0,0);
        gh2 = MFMA16(ah[q], wh2, gh2, 0,0,0);
      }
      int c = kt*16 + u;
      #pragma unroll
      for (int r = 0; r < 4; ++r) {
        int row = g4*4 + r;
        float hp = b2f(hbf[row][c]);
        float h2 = gruh(gi0[r] + bih[c], gi1[r] + bih[256+c], gi2[r] + bih[512+c],
                        gh0[r] + bhh[c], gh1[r] + bhh[256+c], gh2[r] + bhh[512+c], hp);
        h2s[ktl][r] = h2;
        vp[r] += h2 * Wc[c];
        out[((size_t)t*1024 + n0 + row)*STATE_ + 2 + c] = h2;
        if (t == 63) out[((size_t)64*1024 + n0 + row)*STATE_ + 2 + c] = h2;
      }
    }
    #pragma unroll
    for (int r = 0; r < 4; ++r) {
      float s = vp[r];
      s += __shfl_xor(s, 1, 64); s += __shfl_xor(s, 2, 64);
      s += __shfl_xor(s, 4, 64); s += __shfl_xor(s, 8, 64);
      if (u == 0) vred[wv][g4*4 + r] = s;
    }
    __syncthreads();                 // B1: hbf reads + vred writes done
    #pragma unroll
    for (int ktl = 0; ktl < 4; ++ktl) {
      int c = (kb + ktl)*16 + u;
      #pragma unroll
      for (int r = 0; r < 4; ++r) hbf[g4*4 + r][c] = f2b(h2s[ktl][r]);
    }
    if (tid < 16) vfin[tid] = vred[0][tid] + vred[1][tid] + vred[2][tid] + vred[3][tid] + bc[0];
    __syncthreads();                 // B2: new h + vfin ready
    // attention: thread = (n, l)
    int nn = tid >> 4, ll = tid & 15;
    int gn = n0 + nn;
    float w = 0.f;
    const ushort* kr = Ktl + ((size_t)gn*16 + ll)*256;
    #pragma unroll
    for (int q = 0; q < 32; ++q) {
      s16x8 kv = *(const s16x8*)(kr + q*8);
      s16x8 hv = *(const s16x8*)&hbf[nn][q*8];
      #pragma unroll
      for (int jj = 0; jj < 8; ++jj)
        w += b2f((ushort)kv[jj]) * b2f((ushort)hv[jj]);
    }
    float catt;
    if (t == 0) {
      catt = 0.f;
      for (int i = 0; i < 16; ++i) catt += p0[gn*16 + i] * Cm[(size_t)gn*256 + i*16 + ll];
    } else {
      int ap = act[(size_t)(t-1)*1024 + gn];
      catt = Cm[(size_t)gn*256 + ap*16 + ll];
    }
    float ps = (w + wbv[gn*16 + ll]) * catt;
    float mx = ps;
    mx = fmaxf(mx, __shfl_xor(mx, 1, 64)); mx = fmaxf(mx, __shfl_xor(mx, 2, 64));
    mx = fmaxf(mx, __shfl_xor(mx, 4, 64)); mx = fmaxf(mx, __shfl_xor(mx, 8, 64));
    float e = __expf(ps - mx);
    float se = e;
    se += __shfl_xor(se, 1, 64); se += __shfl_xor(se, 2, 64);
    se += __shfl_xor(se, 4, 64); se += __shfl_xor(se, 8, 64);
    float prob = e / se;
    int a = act[(size_t)t*1024 + gn];
    size_t ro = ((size_t)t*1024 + gn)*STATE_;
    out[ro + 258 + ll] = prob;
    out[ro + 274 + ll] = (ll == a) ? 1.f : 0.f;
    if (ll == 0) { out[ro] = (float)a; out[ro + 1] = vfin[nn]; }
    if (t == 63) {
      size_t r2 = ((size_t)64*1024 + gn)*STATE_;
      out[r2 + 258 + ll] = prob;
      out[r2 + 274 + ll] = (ll == a) ? 1.f : 0.f;
      if (ll == 0) { out[r2] = (float)a; out[r2 + 1] = vfin[nn]; }
    }
    __syncthreads();                 // protect vred/hbf for next step
  }
}

extern "C" void kernel_launch(void* const* d_in, const int* in_sizes, int n_in,
                              void* d_out, int out_size, void* d_ws, size_t ws_size,
                              hipStream_t stream){
  (void)in_sizes; (void)n_in; (void)out_size; (void)ws_size;
  const float* cond  = (const float*)d_in[0];
  const int*   lines = (const int*)  d_in[1];
  const int*   act   = (const int*)  d_in[2];
  const float* hxs   = (const float*)d_in[3];
  const float* emb   = (const float*)d_in[4];
  const float* wih_e = (const float*)d_in[5];
  const float* whh_e = (const float*)d_in[6];
  const float* bih_e = (const float*)d_in[7];
  const float* bhh_e = (const float*)d_in[8];
  const float* W1    = (const float*)d_in[9];
  const float* b1    = (const float*)d_in[10];
  const float* W2    = (const float*)d_in[11];
  const float* b2    = (const float*)d_in[12];
  const float* wih_c = (const float*)d_in[13];
  const float* whh_c = (const float*)d_in[14];
  const float* bih_c = (const float*)d_in[15];
  const float* bhh_c = (const float*)d_in[16];
  const float* Wa    = (const float*)d_in[17];
  const float* ba    = (const float*)d_in[18];
  const float* Wc    = (const float*)d_in[19];
  const float* bc    = (const float*)d_in[20];
  float* out = (float*)d_out;

  char* base = (char*)d_ws;
  ushort* Mbf    = (ushort*)(base + 0);           // [16384,256] bf16
  ushort* GiAll  = (ushort*)(base + 8388608);     // [16384,832] bf16
  ushort* Bbf    = (ushort*)(base + 35651584);    // [16,1024,288] bf16
  float*  Km     = (float*) (base + 45088768);    // [16384,256] f32 ([n*16+j][c])
  ushort* Kmbf   = (ushort*)(base + 61865984);    // [16384,256] bf16
  ushort* Ktl    = (ushort*)(base + 70254592);    // [16384,256] bf16
  float*  Cm     = (float*) (base + 78643200);    // [1024,16,16] f32
  float*  hbuf   = (float*) (base + 79691776);    // [1024,256] f32
  float*  p0     = (float*) (base + 80740352);    // [1024,16]
  float*  r0v    = (float*) (base + 80805888);    // [1024,256]
  float*  wbv    = (float*) (base + 81854464);    // [1024,16]
  ushort* wihe_p = (ushort*)(base + 81920000);    // [832,256]
  ushort* whhe_p = (ushort*)(base + 82345984);    // [832,288]
  ushort* wihc_p = (ushort*)(base + 82825216);    // [768,256]
  ushort* whhc_p = (ushort*)(base + 83218432);    // [768,256]
  ushort* W1b    = (ushort*)(base + 83611648);    // [256,320]
  ushort* W2b    = (ushort*)(base + 83775488);    // [256,256]
  ushort* WaTb   = (ushort*)(base + 83906560);    // [256,256]
  ushort* x1     = (ushort*)(base + 84037632);    // [65536,256] bf16
  ushort* xcat   = (ushort*)(base + 8388608);     // overlay (GiAll/Bbf/Km dead by phase 3)
  ushort* x2     = (ushort*)(base + 8388608);     // overlay xcat (dead after W1 gemm)

  hipMemsetAsync(Bbf, 0, (size_t)16*1024*288*2, stream);

  // weight prep
  perm_enc_w<<<832, 256, 0, stream>>>(wih_e, wihe_p, 256, 256, 832*256);
  perm_enc_w<<<936, 256, 0, stream>>>(whh_e, whhe_p, 257, 288, 832*288);
  perm_cell_w<<<768, 256, 0, stream>>>(wih_c, wihc_p);
  perm_cell_w<<<768, 256, 0, stream>>>(whh_c, whhc_p);
  conv_pad_b<<<320, 256, 0, stream>>>(W1, W1b, 256, 320, 320, 256*320);
  conv_pad_b<<<256, 256, 0, stream>>>(W2, W2b, 256, 256, 256, 256*256);
  transp_b<<<256, 256, 0, stream>>>(Wa, WaTb);

  embed_b<<<16384, 256, 0, stream>>>(lines, emb, Mbf);
  init_state<<<1024, 256, 0, stream>>>(hxs, hbuf, p0);
  r0_kernel<<<1024, 256, 0, stream>>>(p0, Mbf, r0v);

  // GiAll = M @ wih_e''^T  (no bias; biases added in gates)
  gemm_mfma<0><<<dim3(256, 13), 256, 0, stream>>>(Mbf, wihe_p, nullptr, GiAll, 256, 832);

  enc1a<<<64, 256, 0, stream>>>(GiAll, whhe_p, bih_e, bhh_e, Bbf);
  enc1b<<<256, 256, 0, stream>>>(GiAll, whhe_p, bih_e, bhh_e, Km, Cm);
  accum_bwd<<<1024, 256, 0, stream>>>(Bbf, Km, Cm);
  wb_kernel<<<1024, 256, 0, stream>>>(Km, ba, wbv);
  km2bf<<<16384, 256, 0, stream>>>(Km, Kmbf);
  gemm_mfma<0><<<dim3(256, 4), 256, 0, stream>>>(Kmbf, WaTb, nullptr, Ktl, 256, 256);

  build_xcat<<<81920, 256, 0, stream>>>(cond, act, r0v, Mbf, xcat);
  gemm_mfma<1><<<dim3(1024, 4), 256, 0, stream>>>(xcat, W1b, b1, x1, 320, 256);
  gemm_mfma<1><<<dim3(1024, 4), 256, 0, stream>>>(x1, W2b, b2, x2, 256, 256);

  cell_persist<<<64, 256, 0, stream>>>(x2, wihc_p, whhc_p, bih_c, bhh_c,
                                       hbuf, p0, act, Ktl, wbv, Cm, Wc, bc, out);
}

// Round 5
// 2525.431 us; speedup vs baseline: 3.6650x; 3.4035x over previous
//
#include <hip/hip_runtime.h>
#include <hip/hip_bf16.h>
#include <cstddef>

#define T_ 64
#define N_ 1024
#define L_ 16
#define H_ 256
#define STATE_ 290

typedef short s16x8 __attribute__((ext_vector_type(8)));
typedef float f32x4 __attribute__((ext_vector_type(4)));
#define MFMA16 __builtin_amdgcn_mfma_f32_16x16x32_bf16

__device__ __forceinline__ float b2f(ushort u){ return __uint_as_float(((unsigned)u) << 16); }
__device__ __forceinline__ ushort f2b(float f){
  unsigned x = __float_as_uint(f);
  return (ushort)((x + 0x7FFFu + ((x >> 16) & 1u)) >> 16);
}
__device__ __forceinline__ float gruh(float gir,float giz,float gig,
                                      float ghr,float ghz,float ghg,float hp){
  float r = 1.f/(1.f + __expf(-(gir + ghr)));
  float z = 1.f/(1.f + __expf(-(giz + ghz)));
  float g = tanhf(gig + r*ghg);
  return (1.f - z)*g + z*hp;
}

// ---------- conversion / prep kernels ----------
__global__ void conv_pad_b(const float* __restrict__ src, ushort* __restrict__ dst,
                           int R, int C, int Cp, int total){
  int idx = blockIdx.x*256 + threadIdx.x;
  if (idx >= total) return;
  int r = idx / Cp, c = idx - r*Cp;
  dst[idx] = (r < R && c < C) ? f2b(src[(size_t)r*C + c]) : (ushort)0;
}
// encoder weights [771, Ci] -> permuted [832, Cp]; dst row d=(3k+p)*16+u <- src row p*257+16k+u
__global__ void perm_enc_w(const float* __restrict__ src, ushort* __restrict__ dst,
                           int Ci, int Cp, int total){
  int idx = blockIdx.x*256 + threadIdx.x;
  if (idx >= total) return;
  int d = idx / Cp, c = idx - d*Cp;
  int tile = d >> 4, u = d & 15;
  int k = tile / 3, p = tile - 3*k;
  int hc = k*16 + u;
  bool ok = (tile < 51) && (hc < 257) && (c < Ci);
  dst[idx] = ok ? f2b(src[(size_t)(p*257 + hc)*Ci + c]) : (ushort)0;
}
// cell weights [768,256] -> permuted [768,256]; dst row (3k+p)*16+u <- src row p*256+16k+u
__global__ void perm_cell_w(const float* __restrict__ src, ushort* __restrict__ dst){
  int idx = blockIdx.x*256 + threadIdx.x;
  if (idx >= 768*256) return;
  int d = idx >> 8, c = idx & 255;
  int tile = d >> 4, u = d & 15;
  int k = tile / 3, p = tile - 3*k;
  dst[idx] = f2b(src[(size_t)(p*256 + k*16 + u)*256 + c]);
}
__global__ void transp_b(const float* __restrict__ Wa, ushort* __restrict__ WaTb){
  int m = blockIdx.x, h = threadIdx.x;
  WaTb[(size_t)h*256 + m] = f2b(Wa[(size_t)m*256 + h]);
}
__global__ void embed_b(const int* __restrict__ lines, const float* __restrict__ emb,
                        ushort* __restrict__ Mbf){
  size_t idx = (size_t)blockIdx.x*256 + threadIdx.x;
  if (idx >= (size_t)N_*L_*H_) return;
  int c = idx & 255; size_t nl = idx >> 8;
  Mbf[idx] = f2b(emb[(size_t)lines[nl]*256 + c]);
}
__global__ void init_state(const float* __restrict__ hxs, float* __restrict__ hbuf,
                           float* __restrict__ p0){
  int n = blockIdx.x, t = threadIdx.x;
  __shared__ int nz;
  if (t == 0) nz = 0;
  __syncthreads();
  for (int c = t; c < STATE_; c += 256)
    if (hxs[(size_t)n*STATE_ + c] != 0.f) atomicOr(&nz, 1);
  __syncthreads();
  bool new_ep = (nz == 0);
  for (int c = t; c < H_; c += 256) hbuf[(size_t)n*H_ + c] = hxs[(size_t)n*STATE_ + 2 + c];
  if (t < L_) {
    float pv = hxs[(size_t)n*STATE_ + 2 + H_ + L_ + t];
    if (t == 0 && new_ep) pv = 1.f;
    p0[n*L_ + t] = pv;
  }
}
__global__ void r0_kernel(const float* __restrict__ p0, const ushort* __restrict__ Mbf,
                          float* __restrict__ r0v){
  int n = blockIdx.x, c = threadIdx.x;
  float s = 0.f;
  for (int l = 0; l < 16; ++l) s += p0[n*16 + l]*b2f(Mbf[((size_t)n*16 + l)*256 + c]);
  r0v[(size_t)n*256 + c] = s;
}
__global__ void km2bf(const float* __restrict__ Km, ushort* __restrict__ Kmbf){
  size_t idx = (size_t)blockIdx.x*256 + threadIdx.x;
  if (idx < (size_t)16384*256) Kmbf[idx] = f2b(Km[idx]);
}
__global__ void build_xcat(const float* __restrict__ cond, const int* __restrict__ act,
                           const float* __restrict__ r0v, const ushort* __restrict__ Mbf,
                           ushort* __restrict__ xcat){
  size_t idx = (size_t)blockIdx.x*256 + threadIdx.x;
  if (idx >= (size_t)T_*N_*320) return;
  int k = (int)(idx % 320);
  size_t row = idx / 320;
  int n = (int)(row & 1023), t = (int)(row >> 10);
  ushort v;
  if (k < 64) v = f2b(cond[row*64 + k]);
  else {
    int c = k - 64;
    if (t == 0) v = f2b(r0v[(size_t)n*256 + c]);
    else { int a = act[(size_t)(t-1)*1024 + n]; v = Mbf[((size_t)n*16 + a)*256 + c]; }
  }
  xcat[idx] = v;
}

// ---------- MFMA GEMM: out[r,col] = act(sum_k A[r,k]*W[col,k] + bias[col]), bf16 out ----------
template<int RELU>
__global__ __launch_bounds__(256) void gemm_mfma(
    const ushort* __restrict__ A, const ushort* __restrict__ W,
    const float* __restrict__ bias, ushort* __restrict__ out,
    int Kd, int ldo){
  int lane = threadIdx.x & 63, wv = threadIdx.x >> 6;
  int u = lane & 15, g4 = lane >> 4;
  int br = blockIdx.x*64 + wv*16;
  int bm = blockIdx.y*64;
  const ushort* Arow = A + (size_t)(br + u)*Kd + g4*8;
  f32x4 acc0 = {0,0,0,0}, acc1 = {0,0,0,0}, acc2 = {0,0,0,0}, acc3 = {0,0,0,0};
  for (int k0 = 0; k0 < Kd; k0 += 32) {
    s16x8 av = *(const s16x8*)(Arow + k0);
    s16x8 b0 = *(const s16x8*)(W + (size_t)(bm +  0 + u)*Kd + k0 + g4*8);
    s16x8 b1 = *(const s16x8*)(W + (size_t)(bm + 16 + u)*Kd + k0 + g4*8);
    s16x8 b2 = *(const s16x8*)(W + (size_t)(bm + 32 + u)*Kd + k0 + g4*8);
    s16x8 b3 = *(const s16x8*)(W + (size_t)(bm + 48 + u)*Kd + k0 + g4*8);
    acc0 = MFMA16(av, b0, acc0, 0,0,0);
    acc1 = MFMA16(av, b1, acc1, 0,0,0);
    acc2 = MFMA16(av, b2, acc2, 0,0,0);
    acc3 = MFMA16(av, b3, acc3, 0,0,0);
  }
  f32x4 ac[4] = {acc0, acc1, acc2, acc3};
  #pragma unroll
  for (int mt = 0; mt < 4; ++mt) {
    int col = bm + mt*16 + u;
    float b = bias ? bias[col] : 0.f;
    #pragma unroll
    for (int r = 0; r < 4; ++r) {
      float v = ac[mt][r] + b;
      if (RELU) v = fmaxf(v, 0.f);
      out[(size_t)(br + g4*4 + r)*ldo + col] = f2b(v);
    }
  }
}

// ---------- backward encoder tile helper ----------
__device__ __forceinline__ void enc1a_tile(int kt, int l, int step, int n0, int u, int g4,
    const ushort hbf[16][328], const ushort* __restrict__ GiAll, const ushort* __restrict__ Wh,
    const float* __restrict__ bih, const float* __restrict__ bhh,
    ushort* __restrict__ Bbf, float (&h2s)[4])
{
  f32x4 a0 = {0,0,0,0}, a1 = {0,0,0,0}, a2 = {0,0,0,0};
  #pragma unroll
  for (int q = 0; q < 9; ++q) {
    int k0 = q*32;
    s16x8 av = *(const s16x8*)&hbf[u][k0 + g4*8];
    s16x8 b0 = *(const s16x8*)(Wh + (size_t)((3*kt+0)*16 + u)*288 + k0 + g4*8);
    s16x8 b1 = *(const s16x8*)(Wh + (size_t)((3*kt+1)*16 + u)*288 + k0 + g4*8);
    s16x8 b2 = *(const s16x8*)(Wh + (size_t)((3*kt+2)*16 + u)*288 + k0 + g4*8);
    a0 = MFMA16(av, b0, a0, 0,0,0);
    a1 = MFMA16(av, b1, a1, 0,0,0);
    a2 = MFMA16(av, b2, a2, 0,0,0);
  }
  int c = kt*16 + u;
  bool cv = (c < 257);
  #pragma unroll
  for (int r = 0; r < 4; ++r) {
    int row = g4*4 + r;
    float hp = b2f(hbf[row][cv ? c : 0]);
    float h2 = hp;
    if (cv) {
      const ushort* gi = GiAll + ((size_t)(n0+row)*16 + l)*832 + 3*kt*16 + u;
      h2 = gruh(b2f(gi[0]) + bih[c], b2f(gi[16]) + bih[257+c], b2f(gi[32]) + bih[514+c],
                a0[r] + bhh[c], a1[r] + bhh[257+c], a2[r] + bhh[514+c], hp);
      Bbf[((size_t)step*1024 + n0 + row)*288 + c] = f2b(h2);
    }
    h2s[r] = h2;
  }
}

// one launch, 64 blocks x 16 n's x 16 waves (wave = col tile), 16 steps
__global__ __launch_bounds__(1024) void enc1a(
    const ushort* __restrict__ GiAll, const ushort* __restrict__ Wh,
    const float* __restrict__ bih, const float* __restrict__ bhh,
    ushort* __restrict__ Bbf){
  __shared__ __align__(16) ushort hbf[16][328];
  int tid = threadIdx.x, lane = tid & 63, wv = tid >> 6;
  int u = lane & 15, g4 = lane >> 4;
  int n0 = blockIdx.x * 16;
  for (int i = tid; i < 16*328; i += 1024) ((ushort*)hbf)[i] = 0;
  __syncthreads();
  for (int step = 0; step < 16; ++step) {
    int l = 15 - step;
    float hA[4], hB[4];
    enc1a_tile(wv, l, step, n0, u, g4, hbf, GiAll, Wh, bih, bhh, Bbf, hA);
    if (wv == 0) enc1a_tile(16, l, step, n0, u, g4, hbf, GiAll, Wh, bih, bhh, Bbf, hB);
    __syncthreads();
    {
      int c = wv*16 + u;
      #pragma unroll
      for (int r = 0; r < 4; ++r) hbf[g4*4 + r][c] = f2b(hA[r]);
      if (wv == 0 && u == 0) {
        #pragma unroll
        for (int r = 0; r < 4; ++r) hbf[g4*4 + r][256] = f2b(hB[r]);
      }
    }
    __syncthreads();
  }
}

// ---------- forward triangular encoder helpers ----------
__device__ __forceinline__ void enc1b_tile(
    int kt, int j, int nb, int u, int g4, int lane,
    const ushort hbf[64][328], const ushort* __restrict__ GiAll, const ushort* __restrict__ Wh,
    const float* __restrict__ bih, const float* __restrict__ bhh,
    float* __restrict__ Km, float* __restrict__ Cm, unsigned (&h2p)[4][2])
{
  f32x4 acc[4][3];
  #pragma unroll
  for (int rt = 0; rt < 4; ++rt){ acc[rt][0]={0,0,0,0}; acc[rt][1]={0,0,0,0}; acc[rt][2]={0,0,0,0}; }
  #pragma unroll
  for (int q = 0; q < 9; ++q) {
    int k0 = q*32;
    s16x8 b0 = *(const s16x8*)(Wh + (size_t)((3*kt+0)*16 + u)*288 + k0 + g4*8);
    s16x8 b1 = *(const s16x8*)(Wh + (size_t)((3*kt+1)*16 + u)*288 + k0 + g4*8);
    s16x8 b2 = *(const s16x8*)(Wh + (size_t)((3*kt+2)*16 + u)*288 + k0 + g4*8);
    #pragma unroll
    for (int rt = 0; rt < 4; ++rt) {
      if (rt*4 > j) continue;
      s16x8 av = *(const s16x8*)&hbf[rt*16 + u][k0 + g4*8];
      acc[rt][0] = MFMA16(av, b0, acc[rt][0], 0,0,0);
      acc[rt][1] = MFMA16(av, b1, acc[rt][1], 0,0,0);
      acc[rt][2] = MFMA16(av, b2, acc[rt][2], 0,0,0);
    }
  }
  int c = kt*16 + u;
  bool cv = (c < 257);
  float kmP[4] = {0.f, 0.f, 0.f, 0.f};
  #pragma unroll
  for (int rt = 0; rt < 4; ++rt) {
    int ii = rt*4 + g4;
    bool act = cv && (ii <= j);
    float h2v[4];
    #pragma unroll
    for (int r = 0; r < 4; ++r) {
      int rowl = rt*16 + g4*4 + r;
      float hp = b2f(hbf[rowl][cv ? c : 0]);
      if (act) {
        const ushort* gi = GiAll + ((size_t)(nb+r)*16 + j)*832 + 3*kt*16 + u;
        h2v[r] = gruh(b2f(gi[0]) + bih[c], b2f(gi[16]) + bih[257+c], b2f(gi[32]) + bih[514+c],
                      acc[rt][0][r] + bhh[c], acc[rt][1][r] + bhh[257+c], acc[rt][2][r] + bhh[514+c], hp);
        if (c < 256) kmP[r] += h2v[r];
        if (c == 256) Cm[(size_t)(nb+r)*256 + ii*16 + j] = h2v[r];
      } else h2v[r] = hp;
    }
    h2p[rt][0] = (unsigned)f2b(h2v[0]) | ((unsigned)f2b(h2v[1]) << 16);
    h2p[rt][1] = (unsigned)f2b(h2v[2]) | ((unsigned)f2b(h2v[3]) << 16);
  }
  if (kt < 16) {
    #pragma unroll
    for (int r = 0; r < 4; ++r) {
      float s = kmP[r];
      s += __shfl_xor(s, 16, 64);
      s += __shfl_xor(s, 32, 64);
      if (lane < 16) Km[((size_t)(nb+r)*16 + j)*256 + c] = s;
    }
  }
}
__device__ __forceinline__ void enc1b_wb(int kt, int j, int u, int g4,
    ushort hbf[64][328], const unsigned (&h2p)[4][2])
{
  int c = kt*16 + u;
  if (c < 257) {
    #pragma unroll
    for (int rt = 0; rt < 4; ++rt) {
      int ii = rt*4 + g4;
      if (ii <= j) {
        hbf[rt*16 + g4*4 + 0][c] = (ushort)(h2p[rt][0] & 0xFFFFu);
        hbf[rt*16 + g4*4 + 1][c] = (ushort)(h2p[rt][0] >> 16);
        hbf[rt*16 + g4*4 + 2][c] = (ushort)(h2p[rt][1] & 0xFFFFu);
        hbf[rt*16 + g4*4 + 3][c] = (ushort)(h2p[rt][1] >> 16);
      }
    }
  }
}

// 256 blocks x (4 n x 16 i) rows x 8 waves, 16 steps
__global__ __launch_bounds__(512) void enc1b(
    const ushort* __restrict__ GiAll, const ushort* __restrict__ Wh,
    const float* __restrict__ bih, const float* __restrict__ bhh,
    float* __restrict__ Km, float* __restrict__ Cm){
  __shared__ __align__(16) ushort hbf[64][328];
  int tid = threadIdx.x, lane = tid & 63, wv = tid >> 6;   // wv 0..7
  int u = lane & 15, g4 = lane >> 4;
  int nb = blockIdx.x * 4;
  for (int i = tid; i < 64*328; i += 512) ((ushort*)hbf)[i] = 0;
  __syncthreads();
  for (int j = 0; j < 16; ++j) {
    unsigned hA[4][2], hB[4][2], hC[4][2];
    enc1b_tile(wv,     j, nb, u, g4, lane, hbf, GiAll, Wh, bih, bhh, Km, Cm, hA);
    enc1b_tile(wv + 8, j, nb, u, g4, lane, hbf, GiAll, Wh, bih, bhh, Km, Cm, hB);
    if (wv == 0) enc1b_tile(16, j, nb, u, g4, lane, hbf, GiAll, Wh, bih, bhh, Km, Cm, hC);
    __syncthreads();
    enc1b_wb(wv,     j, u, g4, hbf, hA);
    enc1b_wb(wv + 8, j, u, g4, hbf, hB);
    if (wv == 0) enc1b_wb(16, j, u, g4, hbf, hC);
    __syncthreads();
  }
}

// ---------- backward-part K accumulate + C fill (i>j) ----------
__global__ void accum_bwd(const ushort* __restrict__ Bbf, float* __restrict__ Km,
                          float* __restrict__ Cm){
  int n = blockIdx.x, c = threadIdx.x;
  float s = 0.f;
  for (int jj = 15; jj >= 0; --jj) {
    if (jj < 15) s += b2f(Bbf[((size_t)(14-jj)*1024 + n)*288 + c]);
    Km[((size_t)n*16 + jj)*256 + c] += s;
  }
  int i = c >> 4, j = c & 15;
  if (i > j) Cm[(size_t)n*256 + i*16 + j] = b2f(Bbf[((size_t)(i-1-j)*1024 + n)*288 + 256]);
}
__global__ void wb_kernel(const float* __restrict__ Km, const float* __restrict__ ba,
                          float* __restrict__ wbv){
  int n = blockIdx.x, t = threadIdx.x;
  int l = t >> 4, lane = t & 15;
  float s = 0.f;
  for (int m = lane; m < 256; m += 16) s += Km[((size_t)n*16 + l)*256 + m]*ba[m];
  s += __shfl_down(s, 8, 16); s += __shfl_down(s, 4, 16);
  s += __shfl_down(s, 2, 16); s += __shfl_down(s, 1, 16);
  if (lane == 0) wbv[n*16 + l] = s;
}

// ---------- phase 4: GRU-only sequential loop. 64 blocks x 1024 threads (wave = col tile) ----------
__global__ __launch_bounds__(1024) void cell_persist(
    const ushort* __restrict__ x2, const ushort* __restrict__ Wi, const ushort* __restrict__ Wh,
    const float* __restrict__ bih, const float* __restrict__ bhh,
    const float* __restrict__ hbuf, const int* __restrict__ act,
    const float* __restrict__ Wc, const float* __restrict__ bc,
    ushort* __restrict__ hcT, float* __restrict__ out){
  __shared__ __align__(16) ushort hbf[16][264];
  __shared__ float vred[16][16];
  int tid = threadIdx.x, lane = tid & 63, wv = tid >> 6;   // wv = kt 0..15
  int u = lane & 15, g4 = lane >> 4;
  int n0 = blockIdx.x * 16;
  for (int i = tid; i < 16*256; i += 1024) {
    int rr = i >> 8, cc = i & 255;
    hbf[rr][cc] = f2b(hbuf[(size_t)(n0 + rr)*256 + cc]);
  }
  const int kt = wv;
  const int c = kt*16 + u;
  float bi0 = bih[c], bi1 = bih[256+c], bi2 = bih[512+c];
  float bh0 = bhh[c], bh1 = bhh[256+c], bh2 = bhh[512+c];
  float wcc = Wc[c];
  float bcv = bc[0];
  const ushort* wip0 = Wi + (size_t)((3*kt+0)*16 + u)*256 + g4*8;
  const ushort* wip1 = Wi + (size_t)((3*kt+1)*16 + u)*256 + g4*8;
  const ushort* wip2 = Wi + (size_t)((3*kt+2)*16 + u)*256 + g4*8;
  const ushort* whp0 = Wh + (size_t)((3*kt+0)*16 + u)*256 + g4*8;
  const ushort* whp1 = Wh + (size_t)((3*kt+1)*16 + u)*256 + g4*8;
  const ushort* whp2 = Wh + (size_t)((3*kt+2)*16 + u)*256 + g4*8;
  __syncthreads();
  for (int t = 0; t < 64; ++t) {
    const ushort* xr = x2 + ((size_t)t*1024 + n0 + u)*256 + g4*8;
    f32x4 gi0={0,0,0,0},gi1={0,0,0,0},gi2={0,0,0,0},gh0={0,0,0,0},gh1={0,0,0,0},gh2={0,0,0,0};
    #pragma unroll
    for (int q = 0; q < 8; ++q) {
      int k0 = q*32;
      s16x8 aiq = *(const s16x8*)(xr + k0);
      s16x8 ahq = *(const s16x8*)&hbf[u][k0 + g4*8];
      s16x8 w0 = *(const s16x8*)(wip0 + k0);
      s16x8 w1 = *(const s16x8*)(wip1 + k0);
      s16x8 w2 = *(const s16x8*)(wip2 + k0);
      s16x8 w3 = *(const s16x8*)(whp0 + k0);
      s16x8 w4 = *(const s16x8*)(whp1 + k0);
      s16x8 w5 = *(const s16x8*)(whp2 + k0);
      gi0 = MFMA16(aiq, w0, gi0, 0,0,0);
      gi1 = MFMA16(aiq, w1, gi1, 0,0,0);
      gi2 = MFMA16(aiq, w2, gi2, 0,0,0);
      gh0 = MFMA16(ahq, w3, gh0, 0,0,0);
      gh1 = MFMA16(ahq, w4, gh1, 0,0,0);
      gh2 = MFMA16(ahq, w5, gh2, 0,0,0);
    }
    float h2s[4];
    #pragma unroll
    for (int r = 0; r < 4; ++r) {
      int row = g4*4 + r;
      float hp = b2f(hbf[row][c]);
      float h2 = gruh(gi0[r]+bi0, gi1[r]+bi1, gi2[r]+bi2,
                      gh0[r]+bh0, gh1[r]+bh1, gh2[r]+bh2, hp);
      h2s[r] = h2;
      out[((size_t)t*1024 + n0 + row)*STATE_ + 2 + c] = h2;
      hcT[((size_t)(n0+row)*64 + t)*256 + c] = f2b(h2);
      if (t == 63) out[((size_t)64*1024 + n0 + row)*STATE_ + 2 + c] = h2;
    }
    #pragma unroll
    for (int r = 0; r < 4; ++r) {
      float s = h2s[r] * wcc;
      s += __shfl_xor(s, 1, 64); s += __shfl_xor(s, 2, 64);
      s += __shfl_xor(s, 4, 64); s += __shfl_xor(s, 8, 64);
      if (u == 0) vred[wv][g4*4 + r] = s;
    }
    __syncthreads();               // hbf reads done, vred written
    #pragma unroll
    for (int r = 0; r < 4; ++r) hbf[g4*4 + r][c] = f2b(h2s[r]);
    if (tid < 16) {
      float s = bcv;
      #pragma unroll
      for (int w = 0; w < 16; ++w) s += vred[w][tid];
      int a = act[(size_t)t*1024 + n0 + tid];
      size_t ro = ((size_t)t*1024 + n0 + tid)*STATE_;
      out[ro] = (float)a; out[ro + 1] = s;
      if (t == 63) {
        size_t r2 = ((size_t)64*1024 + n0 + tid)*STATE_;
        out[r2] = (float)a; out[r2 + 1] = s;
      }
    }
    __syncthreads();               // new h visible; vred reusable
  }
}

// ---------- batched attention/softmax post-pass: block = n, wave = 16 t's ----------
__global__ __launch_bounds__(256) void attn_batch(
    const ushort* __restrict__ Ktl, const ushort* __restrict__ hcT,
    const float* __restrict__ wbv, const float* __restrict__ Cm,
    const float* __restrict__ p0, const int* __restrict__ act,
    float* __restrict__ out){
  int n = blockIdx.x;
  int lane = threadIdx.x & 63, wv = threadIdx.x >> 6;
  int u = lane & 15, g4 = lane >> 4;
  int t0 = wv*16;
  const ushort* Ka = Ktl + ((size_t)n*16 + u)*256 + g4*8;        // A rows = l
  const ushort* Hb = hcT + ((size_t)n*64 + t0 + u)*256 + g4*8;   // B rows = t
  f32x4 acc = {0,0,0,0};
  #pragma unroll
  for (int q = 0; q < 8; ++q) {
    s16x8 av = *(const s16x8*)(Ka + q*32);
    s16x8 bv = *(const s16x8*)(Hb + q*32);
    acc = MFMA16(av, bv, acc, 0,0,0);
  }
  int t = t0 + u;                   // D: col=u -> t, row=g4*4+r -> l
  float ps[4];
  if (t == 0) {
    #pragma unroll
    for (int r = 0; r < 4; ++r) {
      float catt = 0.f;
      for (int i = 0; i < 16; ++i) catt += p0[n*16 + i]*Cm[(size_t)n*256 + i*16 + g4*4 + r];
      ps[r] = (acc[r] + wbv[n*16 + g4*4 + r]) * catt;
    }
  } else {
    int ap = act[(size_t)(t-1)*1024 + n];
    #pragma unroll
    for (int r = 0; r < 4; ++r)
      ps[r] = (acc[r] + wbv[n*16 + g4*4 + r]) * Cm[(size_t)n*256 + ap*16 + g4*4 + r];
  }
  float mx = fmaxf(fmaxf(ps[0], ps[1]), fmaxf(ps[2], ps[3]));
  mx = fmaxf(mx, __shfl_xor(mx, 16, 64));
  mx = fmaxf(mx, __shfl_xor(mx, 32, 64));
  float e[4], se = 0.f;
  #pragma unroll
  for (int r = 0; r < 4; ++r) { e[r] = __expf(ps[r] - mx); se += e[r]; }
  se += __shfl_xor(se, 16, 64);
  se += __shfl_xor(se, 32, 64);
  float inv = 1.f/se;
  int a = act[(size_t)t*1024 + n];
  size_t ro = ((size_t)t*1024 + n)*STATE_;
  #pragma unroll
  for (int r = 0; r < 4; ++r) {
    out[ro + 258 + g4*4 + r] = e[r]*inv;
    out[ro + 274 + g4*4 + r] = (g4*4 + r == a) ? 1.f : 0.f;
  }
  if (t == 63) {
    size_t r2 = ((size_t)64*1024 + n)*STATE_;
    #pragma unroll
    for (int r = 0; r < 4; ++r) {
      out[r2 + 258 + g4*4 + r] = e[r]*inv;
      out[r2 + 274 + g4*4 + r] = (g4*4 + r == a) ? 1.f : 0.f;
    }
  }
}

extern "C" void kernel_launch(void* const* d_in, const int* in_sizes, int n_in,
                              void* d_out, int out_size, void* d_ws, size_t ws_size,
                              hipStream_t stream){
  (void)in_sizes; (void)n_in; (void)out_size; (void)ws_size;
  const float* cond  = (const float*)d_in[0];
  const int*   lines = (const int*)  d_in[1];
  const int*   act   = (const int*)  d_in[2];
  const float* hxs   = (const float*)d_in[3];
  const float* emb   = (const float*)d_in[4];
  const float* wih_e = (const float*)d_in[5];
  const float* whh_e = (const float*)d_in[6];
  const float* bih_e = (const float*)d_in[7];
  const float* bhh_e = (const float*)d_in[8];
  const float* W1    = (const float*)d_in[9];
  const float* b1    = (const float*)d_in[10];
  const float* W2    = (const float*)d_in[11];
  const float* b2    = (const float*)d_in[12];
  const float* wih_c = (const float*)d_in[13];
  const float* whh_c = (const float*)d_in[14];
  const float* bih_c = (const float*)d_in[15];
  const float* bhh_c = (const float*)d_in[16];
  const float* Wa    = (const float*)d_in[17];
  const float* ba    = (const float*)d_in[18];
  const float* Wc    = (const float*)d_in[19];
  const float* bc    = (const float*)d_in[20];
  float* out = (float*)d_out;

  char* base = (char*)d_ws;
  ushort* Mbf    = (ushort*)(base + 0);           // [16384,256] bf16
  ushort* GiAll  = (ushort*)(base + 8388608);     // [16384,832] bf16
  ushort* Bbf    = (ushort*)(base + 35651584);    // [16,1024,288] bf16
  float*  Km     = (float*) (base + 45088768);    // [16384,256] f32
  ushort* Kmbf   = (ushort*)(base + 61865984);    // [16384,256] bf16
  ushort* Ktl    = (ushort*)(base + 70254592);    // [16384,256] bf16
  float*  Cm     = (float*) (base + 78643200);    // [1024,16,16] f32
  float*  hbuf   = (float*) (base + 79691776);    // [1024,256] f32
  float*  p0     = (float*) (base + 80740352);    // [1024,16]
  float*  r0v    = (float*) (base + 80805888);    // [1024,256]
  float*  wbv    = (float*) (base + 81854464);    // [1024,16]
  ushort* wihe_p = (ushort*)(base + 81920000);    // [832,256]
  ushort* whhe_p = (ushort*)(base + 82345984);    // [832,288]
  ushort* wihc_p = (ushort*)(base + 82825216);    // [768,256]
  ushort* whhc_p = (ushort*)(base + 83218432);    // [768,256]
  ushort* W1b    = (ushort*)(base + 83611648);    // [256,320]
  ushort* W2b    = (ushort*)(base + 83775488);    // [256,256]
  ushort* WaTb   = (ushort*)(base + 83906560);    // [256,256]
  ushort* x1     = (ushort*)(base + 84037632);    // [65536,256] bf16 (phase 3)
  ushort* hcT    = (ushort*)(base + 84037632);    // [1024,64,256] bf16 (phase 4, over x1)
  ushort* xcat   = (ushort*)(base + 8388608);     // [65536,320] (over enc buffers, dead)
  ushort* x2     = (ushort*)(base + 8388608);     // [65536,256] (over xcat, dead)

  hipMemsetAsync(Bbf, 0, (size_t)16*1024*288*2, stream);

  perm_enc_w<<<832, 256, 0, stream>>>(wih_e, wihe_p, 256, 256, 832*256);
  perm_enc_w<<<936, 256, 0, stream>>>(whh_e, whhe_p, 257, 288, 832*288);
  perm_cell_w<<<768, 256, 0, stream>>>(wih_c, wihc_p);
  perm_cell_w<<<768, 256, 0, stream>>>(whh_c, whhc_p);
  conv_pad_b<<<320, 256, 0, stream>>>(W1, W1b, 256, 320, 320, 256*320);
  conv_pad_b<<<256, 256, 0, stream>>>(W2, W2b, 256, 256, 256, 256*256);
  transp_b<<<256, 256, 0, stream>>>(Wa, WaTb);

  embed_b<<<16384, 256, 0, stream>>>(lines, emb, Mbf);
  init_state<<<1024, 256, 0, stream>>>(hxs, hbuf, p0);
  r0_kernel<<<1024, 256, 0, stream>>>(p0, Mbf, r0v);

  gemm_mfma<0><<<dim3(256, 13), 256, 0, stream>>>(Mbf, wihe_p, nullptr, GiAll, 256, 832);

  enc1a<<<64, 1024, 0, stream>>>(GiAll, whhe_p, bih_e, bhh_e, Bbf);
  enc1b<<<256, 512, 0, stream>>>(GiAll, whhe_p, bih_e, bhh_e, Km, Cm);
  accum_bwd<<<1024, 256, 0, stream>>>(Bbf, Km, Cm);
  wb_kernel<<<1024, 256, 0, stream>>>(Km, ba, wbv);
  km2bf<<<16384, 256, 0, stream>>>(Km, Kmbf);
  gemm_mfma<0><<<dim3(256, 4), 256, 0, stream>>>(Kmbf, WaTb, nullptr, Ktl, 256, 256);

  build_xcat<<<81920, 256, 0, stream>>>(cond, act, r0v, Mbf, xcat);
  gemm_mfma<1><<<dim3(1024, 4), 256, 0, stream>>>(xcat, W1b, b1, x1, 320, 256);
  gemm_mfma<1><<<dim3(1024, 4), 256, 0, stream>>>(x1, W2b, b2, x2, 256, 256);

  cell_persist<<<64, 1024, 0, stream>>>(x2, wihc_p, whhc_p, bih_c, bhh_c,
                                        hbuf, act, Wc, bc, hcT, out);
  attn_batch<<<1024, 256, 0, stream>>>(Ktl, hcT, wbv, Cm, p0, act, out);
}

// Round 6
// 2386.733 us; speedup vs baseline: 3.8780x; 1.0581x over previous
//
#include <hip/hip_runtime.h>
#include <hip/hip_bf16.h>
#include <cstddef>

#define T_ 64
#define N_ 1024
#define L_ 16
#define H_ 256
#define STATE_ 290

typedef short s16x8 __attribute__((ext_vector_type(8)));
typedef float f32x4 __attribute__((ext_vector_type(4)));
#define MFMA16 __builtin_amdgcn_mfma_f32_16x16x32_bf16

// raw barrier: wait LDS ops only, do NOT drain global stores (that's the
// __syncthreads() vmcnt(0) drain that cost round 5 ~1 ms in cell_persist).
#define BAR() asm volatile("s_waitcnt lgkmcnt(0)\n\ts_barrier" ::: "memory")

__device__ __forceinline__ float b2f(ushort u){ return __uint_as_float(((unsigned)u) << 16); }
__device__ __forceinline__ ushort f2b(float f){
  unsigned x = __float_as_uint(f);
  return (ushort)((x + 0x7FFFu + ((x >> 16) & 1u)) >> 16);
}
__device__ __forceinline__ float gruh(float gir,float giz,float gig,
                                      float ghr,float ghz,float ghg,float hp){
  float r = 1.f/(1.f + __expf(-(gir + ghr)));
  float z = 1.f/(1.f + __expf(-(giz + ghz)));
  float g = tanhf(gig + r*ghg);
  return (1.f - z)*g + z*hp;
}

// ---------- conversion / prep kernels ----------
__global__ void conv_pad_b(const float* __restrict__ src, ushort* __restrict__ dst,
                           int R, int C, int Cp, int total){
  int idx = blockIdx.x*256 + threadIdx.x;
  if (idx >= total) return;
  int r = idx / Cp, c = idx - r*Cp;
  dst[idx] = (r < R && c < C) ? f2b(src[(size_t)r*C + c]) : (ushort)0;
}
// encoder weights [771, Ci] -> permuted [832, Cp]; dst row d=(3k+p)*16+u <- src row p*257+16k+u
__global__ void perm_enc_w(const float* __restrict__ src, ushort* __restrict__ dst,
                           int Ci, int Cp, int total){
  int idx = blockIdx.x*256 + threadIdx.x;
  if (idx >= total) return;
  int d = idx / Cp, c = idx - d*Cp;
  int tile = d >> 4, u = d & 15;
  int k = tile / 3, p = tile - 3*k;
  int hc = k*16 + u;
  bool ok = (tile < 51) && (hc < 257) && (c < Ci);
  dst[idx] = ok ? f2b(src[(size_t)(p*257 + hc)*Ci + c]) : (ushort)0;
}
// cell weights [768,256] -> permuted [768,256]; dst row (3k+p)*16+u <- src row p*256+16k+u
__global__ void perm_cell_w(const float* __restrict__ src, ushort* __restrict__ dst){
  int idx = blockIdx.x*256 + threadIdx.x;
  if (idx >= 768*256) return;
  int d = idx >> 8, c = idx & 255;
  int tile = d >> 4, u = d & 15;
  int k = tile / 3, p = tile - 3*k;
  dst[idx] = f2b(src[(size_t)(p*256 + k*16 + u)*256 + c]);
}
__global__ void transp_b(const float* __restrict__ Wa, ushort* __restrict__ WaTb){
  int m = blockIdx.x, h = threadIdx.x;
  WaTb[(size_t)h*256 + m] = f2b(Wa[(size_t)m*256 + h]);
}
__global__ void embed_b(const int* __restrict__ lines, const float* __restrict__ emb,
                        ushort* __restrict__ Mbf){
  size_t idx = (size_t)blockIdx.x*256 + threadIdx.x;
  if (idx >= (size_t)N_*L_*H_) return;
  int c = idx & 255; size_t nl = idx >> 8;
  Mbf[idx] = f2b(emb[(size_t)lines[nl]*256 + c]);
}
__global__ void init_state(const float* __restrict__ hxs, float* __restrict__ hbuf,
                           float* __restrict__ p0){
  int n = blockIdx.x, t = threadIdx.x;
  __shared__ int nz;
  if (t == 0) nz = 0;
  __syncthreads();
  for (int c = t; c < STATE_; c += 256)
    if (hxs[(size_t)n*STATE_ + c] != 0.f) atomicOr(&nz, 1);
  __syncthreads();
  bool new_ep = (nz == 0);
  for (int c = t; c < H_; c += 256) hbuf[(size_t)n*H_ + c] = hxs[(size_t)n*STATE_ + 2 + c];
  if (t < L_) {
    float pv = hxs[(size_t)n*STATE_ + 2 + H_ + L_ + t];
    if (t == 0 && new_ep) pv = 1.f;
    p0[n*L_ + t] = pv;
  }
}
__global__ void r0_kernel(const float* __restrict__ p0, const ushort* __restrict__ Mbf,
                          float* __restrict__ r0v){
  int n = blockIdx.x, c = threadIdx.x;
  float s = 0.f;
  for (int l = 0; l < 16; ++l) s += p0[n*16 + l]*b2f(Mbf[((size_t)n*16 + l)*256 + c]);
  r0v[(size_t)n*256 + c] = s;
}
__global__ void km2bf(const float* __restrict__ Km, ushort* __restrict__ Kmbf){
  size_t idx = (size_t)blockIdx.x*256 + threadIdx.x;
  if (idx < (size_t)16384*256) Kmbf[idx] = f2b(Km[idx]);
}
__global__ void build_xcat(const float* __restrict__ cond, const int* __restrict__ act,
                           const float* __restrict__ r0v, const ushort* __restrict__ Mbf,
                           ushort* __restrict__ xcat){
  size_t idx = (size_t)blockIdx.x*256 + threadIdx.x;
  if (idx >= (size_t)T_*N_*320) return;
  int k = (int)(idx % 320);
  size_t row = idx / 320;
  int n = (int)(row & 1023), t = (int)(row >> 10);
  ushort v;
  if (k < 64) v = f2b(cond[row*64 + k]);
  else {
    int c = k - 64;
    if (t == 0) v = f2b(r0v[(size_t)n*256 + c]);
    else { int a = act[(size_t)(t-1)*1024 + n]; v = Mbf[((size_t)n*16 + a)*256 + c]; }
  }
  xcat[idx] = v;
}

// ---------- MFMA GEMM: out[r,col] = act(sum_k A[r,k]*W[col,k] + bias[col]), bf16 out ----------
template<int RELU>
__global__ __launch_bounds__(256) void gemm_mfma(
    const ushort* __restrict__ A, const ushort* __restrict__ W,
    const float* __restrict__ bias, ushort* __restrict__ out,
    int Kd, int ldo){
  int lane = threadIdx.x & 63, wv = threadIdx.x >> 6;
  int u = lane & 15, g4 = lane >> 4;
  int br = blockIdx.x*64 + wv*16;
  int bm = blockIdx.y*64;
  const ushort* Arow = A + (size_t)(br + u)*Kd + g4*8;
  f32x4 acc0 = {0,0,0,0}, acc1 = {0,0,0,0}, acc2 = {0,0,0,0}, acc3 = {0,0,0,0};
  for (int k0 = 0; k0 < Kd; k0 += 32) {
    s16x8 av = *(const s16x8*)(Arow + k0);
    s16x8 b0 = *(const s16x8*)(W + (size_t)(bm +  0 + u)*Kd + k0 + g4*8);
    s16x8 b1 = *(const s16x8*)(W + (size_t)(bm + 16 + u)*Kd + k0 + g4*8);
    s16x8 b2 = *(const s16x8*)(W + (size_t)(bm + 32 + u)*Kd + k0 + g4*8);
    s16x8 b3 = *(const s16x8*)(W + (size_t)(bm + 48 + u)*Kd + k0 + g4*8);
    acc0 = MFMA16(av, b0, acc0, 0,0,0);
    acc1 = MFMA16(av, b1, acc1, 0,0,0);
    acc2 = MFMA16(av, b2, acc2, 0,0,0);
    acc3 = MFMA16(av, b3, acc3, 0,0,0);
  }
  f32x4 ac[4] = {acc0, acc1, acc2, acc3};
  #pragma unroll
  for (int mt = 0; mt < 4; ++mt) {
    int col = bm + mt*16 + u;
    float b = bias ? bias[col] : 0.f;
    #pragma unroll
    for (int r = 0; r < 4; ++r) {
      float v = ac[mt][r] + b;
      if (RELU) v = fmaxf(v, 0.f);
      out[(size_t)(br + g4*4 + r)*ldo + col] = f2b(v);
    }
  }
}

// ---------- backward encoder tile helper ----------
__device__ __forceinline__ void enc1a_tile(int kt, int l, int step, int n0, int u, int g4,
    const ushort hbf[16][328], const ushort* __restrict__ GiAll, const ushort* __restrict__ Wh,
    const float* __restrict__ bih, const float* __restrict__ bhh,
    ushort* __restrict__ Bbf, float (&h2s)[4])
{
  f32x4 a0 = {0,0,0,0}, a1 = {0,0,0,0}, a2 = {0,0,0,0};
  #pragma unroll
  for (int q = 0; q < 9; ++q) {
    int k0 = q*32;
    s16x8 av = *(const s16x8*)&hbf[u][k0 + g4*8];
    s16x8 b0 = *(const s16x8*)(Wh + (size_t)((3*kt+0)*16 + u)*288 + k0 + g4*8);
    s16x8 b1 = *(const s16x8*)(Wh + (size_t)((3*kt+1)*16 + u)*288 + k0 + g4*8);
    s16x8 b2 = *(const s16x8*)(Wh + (size_t)((3*kt+2)*16 + u)*288 + k0 + g4*8);
    a0 = MFMA16(av, b0, a0, 0,0,0);
    a1 = MFMA16(av, b1, a1, 0,0,0);
    a2 = MFMA16(av, b2, a2, 0,0,0);
  }
  int c = kt*16 + u;
  bool cv = (c < 257);
  #pragma unroll
  for (int r = 0; r < 4; ++r) {
    int row = g4*4 + r;
    float hp = b2f(hbf[row][cv ? c : 0]);
    float h2 = hp;
    if (cv) {
      const ushort* gi = GiAll + ((size_t)(n0+row)*16 + l)*832 + 3*kt*16 + u;
      h2 = gruh(b2f(gi[0]) + bih[c], b2f(gi[16]) + bih[257+c], b2f(gi[32]) + bih[514+c],
                a0[r] + bhh[c], a1[r] + bhh[257+c], a2[r] + bhh[514+c], hp);
      Bbf[((size_t)step*1024 + n0 + row)*288 + c] = f2b(h2);
    }
    h2s[r] = h2;
  }
}

// one launch, 64 blocks x 16 n's x 16 waves (wave = col tile), 16 steps
__global__ __launch_bounds__(1024) void enc1a(
    const ushort* __restrict__ GiAll, const ushort* __restrict__ Wh,
    const float* __restrict__ bih, const float* __restrict__ bhh,
    ushort* __restrict__ Bbf){
  __shared__ __align__(16) ushort hbf[16][328];
  int tid = threadIdx.x, wv = tid >> 6;
  int lane = tid & 63;
  int u = lane & 15, g4 = lane >> 4;
  int n0 = blockIdx.x * 16;
  for (int i = tid; i < 16*328; i += 1024) ((ushort*)hbf)[i] = 0;
  BAR();
  for (int step = 0; step < 16; ++step) {
    int l = 15 - step;
    float hA[4], hB[4];
    enc1a_tile(wv, l, step, n0, u, g4, hbf, GiAll, Wh, bih, bhh, Bbf, hA);
    if (wv == 0) enc1a_tile(16, l, step, n0, u, g4, hbf, GiAll, Wh, bih, bhh, Bbf, hB);
    BAR();
    {
      int c = wv*16 + u;
      #pragma unroll
      for (int r = 0; r < 4; ++r) hbf[g4*4 + r][c] = f2b(hA[r]);
      if (wv == 0 && u == 0) {
        #pragma unroll
        for (int r = 0; r < 4; ++r) hbf[g4*4 + r][256] = f2b(hB[r]);
      }
    }
    BAR();
  }
}

// ---------- forward triangular encoder helpers ----------
__device__ __forceinline__ void enc1b_tile(
    int kt, int j, int nb, int u, int g4, int lane,
    const ushort hbf[64][328], const ushort* __restrict__ GiAll, const ushort* __restrict__ Wh,
    const float* __restrict__ bih, const float* __restrict__ bhh,
    float* __restrict__ Km, float* __restrict__ Cm, unsigned (&h2p)[4][2])
{
  f32x4 acc[4][3];
  #pragma unroll
  for (int rt = 0; rt < 4; ++rt){ acc[rt][0]={0,0,0,0}; acc[rt][1]={0,0,0,0}; acc[rt][2]={0,0,0,0}; }
  #pragma unroll
  for (int q = 0; q < 9; ++q) {
    int k0 = q*32;
    s16x8 b0 = *(const s16x8*)(Wh + (size_t)((3*kt+0)*16 + u)*288 + k0 + g4*8);
    s16x8 b1 = *(const s16x8*)(Wh + (size_t)((3*kt+1)*16 + u)*288 + k0 + g4*8);
    s16x8 b2 = *(const s16x8*)(Wh + (size_t)((3*kt+2)*16 + u)*288 + k0 + g4*8);
    #pragma unroll
    for (int rt = 0; rt < 4; ++rt) {
      if (rt*4 > j) continue;
      s16x8 av = *(const s16x8*)&hbf[rt*16 + u][k0 + g4*8];
      acc[rt][0] = MFMA16(av, b0, acc[rt][0], 0,0,0);
      acc[rt][1] = MFMA16(av, b1, acc[rt][1], 0,0,0);
      acc[rt][2] = MFMA16(av, b2, acc[rt][2], 0,0,0);
    }
  }
  int c = kt*16 + u;
  bool cv = (c < 257);
  float kmP[4] = {0.f, 0.f, 0.f, 0.f};
  #pragma unroll
  for (int rt = 0; rt < 4; ++rt) {
    int ii = rt*4 + g4;
    bool act = cv && (ii <= j);
    float h2v[4];
    #pragma unroll
    for (int r = 0; r < 4; ++r) {
      int rowl = rt*16 + g4*4 + r;
      float hp = b2f(hbf[rowl][cv ? c : 0]);
      if (act) {
        const ushort* gi = GiAll + ((size_t)(nb+r)*16 + j)*832 + 3*kt*16 + u;
        h2v[r] = gruh(b2f(gi[0]) + bih[c], b2f(gi[16]) + bih[257+c], b2f(gi[32]) + bih[514+c],
                      acc[rt][0][r] + bhh[c], acc[rt][1][r] + bhh[257+c], acc[rt][2][r] + bhh[514+c], hp);
        if (c < 256) kmP[r] += h2v[r];
        if (c == 256) Cm[(size_t)(nb+r)*256 + ii*16 + j] = h2v[r];
      } else h2v[r] = hp;
    }
    h2p[rt][0] = (unsigned)f2b(h2v[0]) | ((unsigned)f2b(h2v[1]) << 16);
    h2p[rt][1] = (unsigned)f2b(h2v[2]) | ((unsigned)f2b(h2v[3]) << 16);
  }
  if (kt < 16) {
    #pragma unroll
    for (int r = 0; r < 4; ++r) {
      float s = kmP[r];
      s += __shfl_xor(s, 16, 64);
      s += __shfl_xor(s, 32, 64);
      if (lane < 16) Km[((size_t)(nb+r)*16 + j)*256 + c] = s;
    }
  }
}
__device__ __forceinline__ void enc1b_wb(int kt, int j, int u, int g4,
    ushort hbf[64][328], const unsigned (&h2p)[4][2])
{
  int c = kt*16 + u;
  if (c < 257) {
    #pragma unroll
    for (int rt = 0; rt < 4; ++rt) {
      int ii = rt*4 + g4;
      if (ii <= j) {
        hbf[rt*16 + g4*4 + 0][c] = (ushort)(h2p[rt][0] & 0xFFFFu);
        hbf[rt*16 + g4*4 + 1][c] = (ushort)(h2p[rt][0] >> 16);
        hbf[rt*16 + g4*4 + 2][c] = (ushort)(h2p[rt][1] & 0xFFFFu);
        hbf[rt*16 + g4*4 + 3][c] = (ushort)(h2p[rt][1] >> 16);
      }
    }
  }
}

// 256 blocks x (4 n x 16 i) rows x 8 waves, 16 steps
__global__ __launch_bounds__(512) void enc1b(
    const ushort* __restrict__ GiAll, const ushort* __restrict__ Wh,
    const float* __restrict__ bih, const float* __restrict__ bhh,
    float* __restrict__ Km, float* __restrict__ Cm){
  __shared__ __align__(16) ushort hbf[64][328];
  int tid = threadIdx.x, lane = tid & 63, wv = tid >> 6;   // wv 0..7
  int u = lane & 15, g4 = lane >> 4;
  int nb = blockIdx.x * 4;
  for (int i = tid; i < 64*328; i += 512) ((ushort*)hbf)[i] = 0;
  BAR();
  for (int j = 0; j < 16; ++j) {
    unsigned hA[4][2], hB[4][2], hC[4][2];
    enc1b_tile(wv,     j, nb, u, g4, lane, hbf, GiAll, Wh, bih, bhh, Km, Cm, hA);
    enc1b_tile(wv + 8, j, nb, u, g4, lane, hbf, GiAll, Wh, bih, bhh, Km, Cm, hB);
    if (wv == 0) enc1b_tile(16, j, nb, u, g4, lane, hbf, GiAll, Wh, bih, bhh, Km, Cm, hC);
    BAR();
    enc1b_wb(wv,     j, u, g4, hbf, hA);
    enc1b_wb(wv + 8, j, u, g4, hbf, hB);
    if (wv == 0) enc1b_wb(16, j, u, g4, hbf, hC);
    BAR();
  }
}

// ---------- backward-part K accumulate + C fill (i>j) ----------
__global__ void accum_bwd(const ushort* __restrict__ Bbf, float* __restrict__ Km,
                          float* __restrict__ Cm){
  int n = blockIdx.x, c = threadIdx.x;
  float s = 0.f;
  for (int jj = 15; jj >= 0; --jj) {
    if (jj < 15) s += b2f(Bbf[((size_t)(14-jj)*1024 + n)*288 + c]);
    Km[((size_t)n*16 + jj)*256 + c] += s;
  }
  int i = c >> 4, j = c & 15;
  if (i > j) Cm[(size_t)n*256 + i*16 + j] = b2f(Bbf[((size_t)(i-1-j)*1024 + n)*288 + 256]);
}
__global__ void wb_kernel(const float* __restrict__ Km, const float* __restrict__ ba,
                          float* __restrict__ wbv){
  int n = blockIdx.x, t = threadIdx.x;
  int l = t >> 4, lane = t & 15;
  float s = 0.f;
  for (int m = lane; m < 256; m += 16) s += Km[((size_t)n*16 + l)*256 + m]*ba[m];
  s += __shfl_down(s, 8, 16); s += __shfl_down(s, 4, 16);
  s += __shfl_down(s, 2, 16); s += __shfl_down(s, 1, 16);
  if (lane == 0) wbv[n*16 + l] = s;
}

// ---------- phase 4: pure h-chain. 64 blocks x 1024 threads (wave = col tile) ----------
// Double-buffered LDS h, ONE lgkm-only barrier per step; only global write is hcT (bf16).
__global__ __launch_bounds__(1024) void cell_persist(
    const ushort* __restrict__ x2, const ushort* __restrict__ Wi, const ushort* __restrict__ Wh,
    const float* __restrict__ bih, const float* __restrict__ bhh,
    const float* __restrict__ hbuf, ushort* __restrict__ hcT){
  __shared__ __align__(16) ushort hbf[2][16][264];
  int tid = threadIdx.x, lane = tid & 63, wv = tid >> 6;   // wv = kt 0..15
  int u = lane & 15, g4 = lane >> 4;
  int n0 = blockIdx.x * 16;
  for (int i = tid; i < 16*256; i += 1024) {
    int rr = i >> 8, cc = i & 255;
    hbf[0][rr][cc] = f2b(hbuf[(size_t)(n0 + rr)*256 + cc]);
  }
  const int kt = wv;
  const int c = kt*16 + u;
  float bi0 = bih[c], bi1 = bih[256+c], bi2 = bih[512+c];
  float bh0 = bhh[c], bh1 = bhh[256+c], bh2 = bhh[512+c];
  const ushort* wip0 = Wi + (size_t)((3*kt+0)*16 + u)*256 + g4*8;
  const ushort* wip1 = Wi + (size_t)((3*kt+1)*16 + u)*256 + g4*8;
  const ushort* wip2 = Wi + (size_t)((3*kt+2)*16 + u)*256 + g4*8;
  const ushort* whp0 = Wh + (size_t)((3*kt+0)*16 + u)*256 + g4*8;
  const ushort* whp1 = Wh + (size_t)((3*kt+1)*16 + u)*256 + g4*8;
  const ushort* whp2 = Wh + (size_t)((3*kt+2)*16 + u)*256 + g4*8;
  BAR();
  int cur = 0;
  for (int t = 0; t < 64; ++t) {
    const ushort* xr = x2 + ((size_t)t*1024 + n0 + u)*256 + g4*8;
    f32x4 gi0={0,0,0,0},gi1={0,0,0,0},gi2={0,0,0,0},gh0={0,0,0,0},gh1={0,0,0,0},gh2={0,0,0,0};
    #pragma unroll
    for (int q = 0; q < 8; ++q) {
      int k0 = q*32;
      s16x8 aiq = *(const s16x8*)(xr + k0);
      s16x8 ahq = *(const s16x8*)&hbf[cur][u][k0 + g4*8];
      s16x8 w0 = *(const s16x8*)(wip0 + k0);
      s16x8 w1 = *(const s16x8*)(wip1 + k0);
      s16x8 w2 = *(const s16x8*)(wip2 + k0);
      s16x8 w3 = *(const s16x8*)(whp0 + k0);
      s16x8 w4 = *(const s16x8*)(whp1 + k0);
      s16x8 w5 = *(const s16x8*)(whp2 + k0);
      gi0 = MFMA16(aiq, w0, gi0, 0,0,0);
      gi1 = MFMA16(aiq, w1, gi1, 0,0,0);
      gi2 = MFMA16(aiq, w2, gi2, 0,0,0);
      gh0 = MFMA16(ahq, w3, gh0, 0,0,0);
      gh1 = MFMA16(ahq, w4, gh1, 0,0,0);
      gh2 = MFMA16(ahq, w5, gh2, 0,0,0);
    }
    #pragma unroll
    for (int r = 0; r < 4; ++r) {
      int row = g4*4 + r;
      float hp = b2f(hbf[cur][row][c]);
      float h2 = gruh(gi0[r]+bi0, gi1[r]+bi1, gi2[r]+bi2,
                      gh0[r]+bh0, gh1[r]+bh1, gh2[r]+bh2, hp);
      ushort hb = f2b(h2);
      hbf[cur^1][row][c] = hb;
      hcT[((size_t)(n0+row)*64 + t)*256 + c] = hb;   // fire-and-forget
    }
    BAR();
    cur ^= 1;
  }
}

// ---------- output post-pass: h (f32), a, v columns; incl. duplicate row tt=64 ----------
__global__ __launch_bounds__(256) void hv_out(
    const ushort* __restrict__ hcT, const int* __restrict__ act,
    const float* __restrict__ Wc, const float* __restrict__ bc,
    float* __restrict__ out){
  int b = blockIdx.x;                 // 0 .. 65*1024-1
  int tt = b >> 10, n = b & 1023;
  int t = tt > 63 ? 63 : tt;
  int c = threadIdx.x;
  float h = b2f(hcT[((size_t)n*64 + t)*256 + c]);
  size_t ro = ((size_t)tt*1024 + n)*STATE_;
  out[ro + 2 + c] = h;
  float s = h * Wc[c];
  #pragma unroll
  for (int off = 32; off > 0; off >>= 1) s += __shfl_down(s, off, 64);
  __shared__ float red[4];
  if ((c & 63) == 0) red[c >> 6] = s;
  __syncthreads();
  if (c == 0) {
    out[ro]     = (float)act[(size_t)t*1024 + n];
    out[ro + 1] = red[0] + red[1] + red[2] + red[3] + bc[0];
  }
}

// ---------- batched attention/softmax post-pass: block = n, wave = 16 t's ----------
__global__ __launch_bounds__(256) void attn_batch(
    const ushort* __restrict__ Ktl, const ushort* __restrict__ hcT,
    const float* __restrict__ wbv, const float* __restrict__ Cm,
    const float* __restrict__ p0, const int* __restrict__ act,
    float* __restrict__ out){
  int n = blockIdx.x;
  int lane = threadIdx.x & 63, wv = threadIdx.x >> 6;
  int u = lane & 15, g4 = lane >> 4;
  int t0 = wv*16;
  const ushort* Ka = Ktl + ((size_t)n*16 + u)*256 + g4*8;        // A rows = l
  const ushort* Hb = hcT + ((size_t)n*64 + t0 + u)*256 + g4*8;   // B rows = t
  f32x4 acc = {0,0,0,0};
  #pragma unroll
  for (int q = 0; q < 8; ++q) {
    s16x8 av = *(const s16x8*)(Ka + q*32);
    s16x8 bv = *(const s16x8*)(Hb + q*32);
    acc = MFMA16(av, bv, acc, 0,0,0);
  }
  int t = t0 + u;                   // D: col=u -> t, row=g4*4+r -> l
  float ps[4];
  if (t == 0) {
    #pragma unroll
    for (int r = 0; r < 4; ++r) {
      float catt = 0.f;
      for (int i = 0; i < 16; ++i) catt += p0[n*16 + i]*Cm[(size_t)n*256 + i*16 + g4*4 + r];
      ps[r] = (acc[r] + wbv[n*16 + g4*4 + r]) * catt;
    }
  } else {
    int ap = act[(size_t)(t-1)*1024 + n];
    #pragma unroll
    for (int r = 0; r < 4; ++r)
      ps[r] = (acc[r] + wbv[n*16 + g4*4 + r]) * Cm[(size_t)n*256 + ap*16 + g4*4 + r];
  }
  float mx = fmaxf(fmaxf(ps[0], ps[1]), fmaxf(ps[2], ps[3]));
  mx = fmaxf(mx, __shfl_xor(mx, 16, 64));
  mx = fmaxf(mx, __shfl_xor(mx, 32, 64));
  float e[4], se = 0.f;
  #pragma unroll
  for (int r = 0; r < 4; ++r) { e[r] = __expf(ps[r] - mx); se += e[r]; }
  se += __shfl_xor(se, 16, 64);
  se += __shfl_xor(se, 32, 64);
  float inv = 1.f/se;
  int a = act[(size_t)t*1024 + n];
  size_t ro = ((size_t)t*1024 + n)*STATE_;
  #pragma unroll
  for (int r = 0; r < 4; ++r) {
    out[ro + 258 + g4*4 + r] = e[r]*inv;
    out[ro + 274 + g4*4 + r] = (g4*4 + r == a) ? 1.f : 0.f;
  }
  if (t == 63) {
    size_t r2 = ((size_t)64*1024 + n)*STATE_;
    #pragma unroll
    for (int r = 0; r < 4; ++r) {
      out[r2 + 258 + g4*4 + r] = e[r]*inv;
      out[r2 + 274 + g4*4 + r] = (g4*4 + r == a) ? 1.f : 0.f;
    }
  }
}

extern "C" void kernel_launch(void* const* d_in, const int* in_sizes, int n_in,
                              void* d_out, int out_size, void* d_ws, size_t ws_size,
                              hipStream_t stream){
  (void)in_sizes; (void)n_in; (void)out_size; (void)ws_size;
  const float* cond  = (const float*)d_in[0];
  const int*   lines = (const int*)  d_in[1];
  const int*   act   = (const int*)  d_in[2];
  const float* hxs   = (const float*)d_in[3];
  const float* emb   = (const float*)d_in[4];
  const float* wih_e = (const float*)d_in[5];
  const float* whh_e = (const float*)d_in[6];
  const float* bih_e = (const float*)d_in[7];
  const float* bhh_e = (const float*)d_in[8];
  const float* W1    = (const float*)d_in[9];
  const float* b1    = (const float*)d_in[10];
  const float* W2    = (const float*)d_in[11];
  const float* b2    = (const float*)d_in[12];
  const float* wih_c = (const float*)d_in[13];
  const float* whh_c = (const float*)d_in[14];
  const float* bih_c = (const float*)d_in[15];
  const float* bhh_c = (const float*)d_in[16];
  const float* Wa    = (const float*)d_in[17];
  const float* ba    = (const float*)d_in[18];
  const float* Wc    = (const float*)d_in[19];
  const float* bc    = (const float*)d_in[20];
  float* out = (float*)d_out;

  char* base = (char*)d_ws;
  ushort* Mbf    = (ushort*)(base + 0);           // [16384,256] bf16
  ushort* GiAll  = (ushort*)(base + 8388608);     // [16384,832] bf16
  ushort* Bbf    = (ushort*)(base + 35651584);    // [16,1024,288] bf16
  float*  Km     = (float*) (base + 45088768);    // [16384,256] f32
  ushort* Kmbf   = (ushort*)(base + 61865984);    // [16384,256] bf16
  ushort* Ktl    = (ushort*)(base + 70254592);    // [16384,256] bf16
  float*  Cm     = (float*) (base + 78643200);    // [1024,16,16] f32
  float*  hbuf   = (float*) (base + 79691776);    // [1024,256] f32
  float*  p0     = (float*) (base + 80740352);    // [1024,16]
  float*  r0v    = (float*) (base + 80805888);    // [1024,256]
  float*  wbv    = (float*) (base + 81854464);    // [1024,16]
  ushort* wihe_p = (ushort*)(base + 81920000);    // [832,256]
  ushort* whhe_p = (ushort*)(base + 82345984);    // [832,288]
  ushort* wihc_p = (ushort*)(base + 82825216);    // [768,256]
  ushort* whhc_p = (ushort*)(base + 83218432);    // [768,256]
  ushort* W1b    = (ushort*)(base + 83611648);    // [256,320]
  ushort* W2b    = (ushort*)(base + 83775488);    // [256,256]
  ushort* WaTb   = (ushort*)(base + 83906560);    // [256,256]
  ushort* x1     = (ushort*)(base + 84037632);    // [65536,256] bf16 (phase 3)
  ushort* hcT    = (ushort*)(base + 84037632);    // [1024,64,256] bf16 (phase 4, over x1)
  ushort* xcat   = (ushort*)(base + 8388608);     // [65536,320] (over enc buffers, dead)
  ushort* x2     = (ushort*)(base + 8388608);     // [65536,256] (over xcat, dead)

  hipMemsetAsync(Bbf, 0, (size_t)16*1024*288*2, stream);

  perm_enc_w<<<832, 256, 0, stream>>>(wih_e, wihe_p, 256, 256, 832*256);
  perm_enc_w<<<936, 256, 0, stream>>>(whh_e, whhe_p, 257, 288, 832*288);
  perm_cell_w<<<768, 256, 0, stream>>>(wih_c, wihc_p);
  perm_cell_w<<<768, 256, 0, stream>>>(whh_c, whhc_p);
  conv_pad_b<<<320, 256, 0, stream>>>(W1, W1b, 256, 320, 320, 256*320);
  conv_pad_b<<<256, 256, 0, stream>>>(W2, W2b, 256, 256, 256, 256*256);
  transp_b<<<256, 256, 0, stream>>>(Wa, WaTb);

  embed_b<<<16384, 256, 0, stream>>>(lines, emb, Mbf);
  init_state<<<1024, 256, 0, stream>>>(hxs, hbuf, p0);
  r0_kernel<<<1024, 256, 0, stream>>>(p0, Mbf, r0v);

  gemm_mfma<0><<<dim3(256, 13), 256, 0, stream>>>(Mbf, wihe_p, nullptr, GiAll, 256, 832);

  enc1a<<<64, 1024, 0, stream>>>(GiAll, whhe_p, bih_e, bhh_e, Bbf);
  enc1b<<<256, 512, 0, stream>>>(GiAll, whhe_p, bih_e, bhh_e, Km, Cm);
  accum_bwd<<<1024, 256, 0, stream>>>(Bbf, Km, Cm);
  wb_kernel<<<1024, 256, 0, stream>>>(Km, ba, wbv);
  km2bf<<<16384, 256, 0, stream>>>(Km, Kmbf);
  gemm_mfma<0><<<dim3(256, 4), 256, 0, stream>>>(Kmbf, WaTb, nullptr, Ktl, 256, 256);

  build_xcat<<<81920, 256, 0, stream>>>(cond, act, r0v, Mbf, xcat);
  gemm_mfma<1><<<dim3(1024, 4), 256, 0, stream>>>(xcat, W1b, b1, x1, 320, 256);
  gemm_mfma<1><<<dim3(1024, 4), 256, 0, stream>>>(x1, W2b, b2, x2, 256, 256);

  cell_persist<<<64, 1024, 0, stream>>>(x2, wihc_p, whhc_p, bih_c, bhh_c, hbuf, hcT);

  hv_out<<<65*1024, 256, 0, stream>>>(hcT, act, Wc, bc, out);
  attn_batch<<<1024, 256, 0, stream>>>(Ktl, hcT, wbv, Cm, p0, act, out);
}

// Round 7
// 1840.595 us; speedup vs baseline: 5.0287x; 1.2967x over previous
//
#include <hip/hip_runtime.h>
#include <hip/hip_bf16.h>
#include <cstddef>

#define T_ 64
#define N_ 1024
#define L_ 16
#define H_ 256
#define STATE_ 290

typedef short s16x8 __attribute__((ext_vector_type(8)));
typedef float f32x4 __attribute__((ext_vector_type(4)));
typedef ushort us4 __attribute__((ext_vector_type(4)));
#define MFMA16 __builtin_amdgcn_mfma_f32_16x16x32_bf16

// raw barrier: wait LDS ops only, do NOT drain global stores.
#define BAR() asm volatile("s_waitcnt lgkmcnt(0)\n\ts_barrier" ::: "memory")

__device__ __forceinline__ float b2f(ushort u){ return __uint_as_float(((unsigned)u) << 16); }
__device__ __forceinline__ ushort f2b(float f){
  unsigned x = __float_as_uint(f);
  return (ushort)((x + 0x7FFFu + ((x >> 16) & 1u)) >> 16);
}
__device__ __forceinline__ float gruh(float gir,float giz,float gig,
                                      float ghr,float ghz,float ghg,float hp){
  float r = 1.f/(1.f + __expf(-(gir + ghr)));
  float z = 1.f/(1.f + __expf(-(giz + ghz)));
  float g = tanhf(gig + r*ghg);
  return (1.f - z)*g + z*hp;
}

// ---------- conversion / prep kernels ----------
__global__ void conv_pad_b(const float* __restrict__ src, ushort* __restrict__ dst,
                           int R, int C, int Cp, int total){
  int idx = blockIdx.x*256 + threadIdx.x;
  if (idx >= total) return;
  int r = idx / Cp, c = idx - r*Cp;
  dst[idx] = (r < R && c < C) ? f2b(src[(size_t)r*C + c]) : (ushort)0;
}
__global__ void perm_enc_w(const float* __restrict__ src, ushort* __restrict__ dst,
                           int Ci, int Cp, int total){
  int idx = blockIdx.x*256 + threadIdx.x;
  if (idx >= total) return;
  int d = idx / Cp, c = idx - d*Cp;
  int tile = d >> 4, u = d & 15;
  int k = tile / 3, p = tile - 3*k;
  int hc = k*16 + u;
  bool ok = (tile < 51) && (hc < 257) && (c < Ci);
  dst[idx] = ok ? f2b(src[(size_t)(p*257 + hc)*Ci + c]) : (ushort)0;
}
__global__ void perm_cell_w(const float* __restrict__ src, ushort* __restrict__ dst){
  int idx = blockIdx.x*256 + threadIdx.x;
  if (idx >= 768*256) return;
  int d = idx >> 8, c = idx & 255;
  int tile = d >> 4, u = d & 15;
  int k = tile / 3, p = tile - 3*k;
  dst[idx] = f2b(src[(size_t)(p*256 + k*16 + u)*256 + c]);
}
// combined bias for gi GEMM (permuted layout); g-gate gets bih only (bhh_g multiplied by r)
__global__ void cbias_k(const float* __restrict__ bih, const float* __restrict__ bhh,
                        float* __restrict__ cb){
  int d = blockIdx.x*256 + threadIdx.x;
  if (d >= 768) return;
  int tile = d >> 4, u = d & 15;
  int k = tile / 3, p = tile - 3*k;
  int src = p*256 + k*16 + u;
  cb[d] = bih[src] + (p < 2 ? bhh[src] : 0.f);
}
__global__ void transp_b(const float* __restrict__ Wa, ushort* __restrict__ WaTb){
  int m = blockIdx.x, h = threadIdx.x;
  WaTb[(size_t)h*256 + m] = f2b(Wa[(size_t)m*256 + h]);
}
__global__ void embed_b(const int* __restrict__ lines, const float* __restrict__ emb,
                        ushort* __restrict__ Mbf){
  size_t idx = (size_t)blockIdx.x*256 + threadIdx.x;
  if (idx >= (size_t)N_*L_*H_) return;
  int c = idx & 255; size_t nl = idx >> 8;
  Mbf[idx] = f2b(emb[(size_t)lines[nl]*256 + c]);
}
__global__ void init_state(const float* __restrict__ hxs, float* __restrict__ hbuf,
                           float* __restrict__ p0){
  int n = blockIdx.x, t = threadIdx.x;
  __shared__ int nz;
  if (t == 0) nz = 0;
  __syncthreads();
  for (int c = t; c < STATE_; c += 256)
    if (hxs[(size_t)n*STATE_ + c] != 0.f) atomicOr(&nz, 1);
  __syncthreads();
  bool new_ep = (nz == 0);
  for (int c = t; c < H_; c += 256) hbuf[(size_t)n*H_ + c] = hxs[(size_t)n*STATE_ + 2 + c];
  if (t < L_) {
    float pv = hxs[(size_t)n*STATE_ + 2 + H_ + L_ + t];
    if (t == 0 && new_ep) pv = 1.f;
    p0[n*L_ + t] = pv;
  }
}
__global__ void r0_kernel(const float* __restrict__ p0, const ushort* __restrict__ Mbf,
                          float* __restrict__ r0v){
  int n = blockIdx.x, c = threadIdx.x;
  float s = 0.f;
  for (int l = 0; l < 16; ++l) s += p0[n*16 + l]*b2f(Mbf[((size_t)n*16 + l)*256 + c]);
  r0v[(size_t)n*256 + c] = s;
}
__global__ void km2bf(const float* __restrict__ Km, ushort* __restrict__ Kmbf){
  size_t idx = (size_t)blockIdx.x*256 + threadIdx.x;
  if (idx < (size_t)16384*256) Kmbf[idx] = f2b(Km[idx]);
}
__global__ void build_xcat(const float* __restrict__ cond, const int* __restrict__ act,
                           const float* __restrict__ r0v, const ushort* __restrict__ Mbf,
                           ushort* __restrict__ xcat){
  size_t idx = (size_t)blockIdx.x*256 + threadIdx.x;
  if (idx >= (size_t)T_*N_*320) return;
  int k = (int)(idx % 320);
  size_t row = idx / 320;
  int n = (int)(row & 1023), t = (int)(row >> 10);
  ushort v;
  if (k < 64) v = f2b(cond[row*64 + k]);
  else {
    int c = k - 64;
    if (t == 0) v = f2b(r0v[(size_t)n*256 + c]);
    else { int a = act[(size_t)(t-1)*1024 + n]; v = Mbf[((size_t)n*16 + a)*256 + c]; }
  }
  xcat[idx] = v;
}

// ---------- MFMA GEMM: out[r,col] = act(sum_k A[r,k]*W[col,k] + bias[col]), bf16 out ----------
template<int RELU>
__global__ __launch_bounds__(256) void gemm_mfma(
    const ushort* __restrict__ A, const ushort* __restrict__ W,
    const float* __restrict__ bias, ushort* __restrict__ out,
    int Kd, int ldo){
  int lane = threadIdx.x & 63, wv = threadIdx.x >> 6;
  int u = lane & 15, g4 = lane >> 4;
  int br = blockIdx.x*64 + wv*16;
  int bm = blockIdx.y*64;
  const ushort* Arow = A + (size_t)(br + u)*Kd + g4*8;
  f32x4 acc0 = {0,0,0,0}, acc1 = {0,0,0,0}, acc2 = {0,0,0,0}, acc3 = {0,0,0,0};
  for (int k0 = 0; k0 < Kd; k0 += 32) {
    s16x8 av = *(const s16x8*)(Arow + k0);
    s16x8 b0 = *(const s16x8*)(W + (size_t)(bm +  0 + u)*Kd + k0 + g4*8);
    s16x8 b1 = *(const s16x8*)(W + (size_t)(bm + 16 + u)*Kd + k0 + g4*8);
    s16x8 b2 = *(const s16x8*)(W + (size_t)(bm + 32 + u)*Kd + k0 + g4*8);
    s16x8 b3 = *(const s16x8*)(W + (size_t)(bm + 48 + u)*Kd + k0 + g4*8);
    acc0 = MFMA16(av, b0, acc0, 0,0,0);
    acc1 = MFMA16(av, b1, acc1, 0,0,0);
    acc2 = MFMA16(av, b2, acc2, 0,0,0);
    acc3 = MFMA16(av, b3, acc3, 0,0,0);
  }
  f32x4 ac[4] = {acc0, acc1, acc2, acc3};
  #pragma unroll
  for (int mt = 0; mt < 4; ++mt) {
    int col = bm + mt*16 + u;
    float b = bias ? bias[col] : 0.f;
    #pragma unroll
    for (int r = 0; r < 4; ++r) {
      float v = ac[mt][r] + b;
      if (RELU) v = fmaxf(v, 0.f);
      out[(size_t)(br + g4*4 + r)*ldo + col] = f2b(v);
    }
  }
}

// ---------- backward encoder ----------
__device__ __forceinline__ void enc1a_tile(int kt, int l, int step, int n0, int u, int g4,
    const ushort hbf[16][328], const ushort* __restrict__ GiAll, const ushort* __restrict__ Wh,
    const float* __restrict__ bih, const float* __restrict__ bhh,
    ushort* __restrict__ Bbf, float (&h2s)[4])
{
  f32x4 a0 = {0,0,0,0}, a1 = {0,0,0,0}, a2 = {0,0,0,0};
  #pragma unroll
  for (int q = 0; q < 9; ++q) {
    int k0 = q*32;
    s16x8 av = *(const s16x8*)&hbf[u][k0 + g4*8];
    s16x8 b0 = *(const s16x8*)(Wh + (size_t)((3*kt+0)*16 + u)*288 + k0 + g4*8);
    s16x8 b1 = *(const s16x8*)(Wh + (size_t)((3*kt+1)*16 + u)*288 + k0 + g4*8);
    s16x8 b2 = *(const s16x8*)(Wh + (size_t)((3*kt+2)*16 + u)*288 + k0 + g4*8);
    a0 = MFMA16(av, b0, a0, 0,0,0);
    a1 = MFMA16(av, b1, a1, 0,0,0);
    a2 = MFMA16(av, b2, a2, 0,0,0);
  }
  int c = kt*16 + u;
  bool cv = (c < 257);
  #pragma unroll
  for (int r = 0; r < 4; ++r) {
    int row = g4*4 + r;
    float hp = b2f(hbf[row][cv ? c : 0]);
    float h2 = hp;
    if (cv) {
      const ushort* gi = GiAll + ((size_t)(n0+row)*16 + l)*832 + 3*kt*16 + u;
      h2 = gruh(b2f(gi[0]) + bih[c], b2f(gi[16]) + bih[257+c], b2f(gi[32]) + bih[514+c],
                a0[r] + bhh[c], a1[r] + bhh[257+c], a2[r] + bhh[514+c], hp);
      Bbf[((size_t)step*1024 + n0 + row)*288 + c] = f2b(h2);
    }
    h2s[r] = h2;
  }
}
__global__ __launch_bounds__(1024) void enc1a(
    const ushort* __restrict__ GiAll, const ushort* __restrict__ Wh,
    const float* __restrict__ bih, const float* __restrict__ bhh,
    ushort* __restrict__ Bbf){
  __shared__ __align__(16) ushort hbf[16][328];
  int tid = threadIdx.x, wv = tid >> 6;
  int lane = tid & 63;
  int u = lane & 15, g4 = lane >> 4;
  int n0 = blockIdx.x * 16;
  for (int i = tid; i < 16*328; i += 1024) ((ushort*)hbf)[i] = 0;
  BAR();
  for (int step = 0; step < 16; ++step) {
    int l = 15 - step;
    float hA[4], hB[4];
    enc1a_tile(wv, l, step, n0, u, g4, hbf, GiAll, Wh, bih, bhh, Bbf, hA);
    if (wv == 0) enc1a_tile(16, l, step, n0, u, g4, hbf, GiAll, Wh, bih, bhh, Bbf, hB);
    BAR();
    {
      int c = wv*16 + u;
      #pragma unroll
      for (int r = 0; r < 4; ++r) hbf[g4*4 + r][c] = f2b(hA[r]);
      if (wv == 0 && u == 0) {
        #pragma unroll
        for (int r = 0; r < 4; ++r) hbf[g4*4 + r][256] = f2b(hB[r]);
      }
    }
    BAR();
  }
}

// ---------- forward triangular encoder ----------
__device__ __forceinline__ void enc1b_tile(
    int kt, int j, int nb, int u, int g4, int lane,
    const ushort hbf[64][328], const ushort* __restrict__ GiAll, const ushort* __restrict__ Wh,
    const float* __restrict__ bih, const float* __restrict__ bhh,
    float* __restrict__ Km, float* __restrict__ Cm, unsigned (&h2p)[4][2])
{
  f32x4 acc[4][3];
  #pragma unroll
  for (int rt = 0; rt < 4; ++rt){ acc[rt][0]={0,0,0,0}; acc[rt][1]={0,0,0,0}; acc[rt][2]={0,0,0,0}; }
  #pragma unroll
  for (int q = 0; q < 9; ++q) {
    int k0 = q*32;
    s16x8 b0 = *(const s16x8*)(Wh + (size_t)((3*kt+0)*16 + u)*288 + k0 + g4*8);
    s16x8 b1 = *(const s16x8*)(Wh + (size_t)((3*kt+1)*16 + u)*288 + k0 + g4*8);
    s16x8 b2 = *(const s16x8*)(Wh + (size_t)((3*kt+2)*16 + u)*288 + k0 + g4*8);
    #pragma unroll
    for (int rt = 0; rt < 4; ++rt) {
      if (rt*4 > j) continue;
      s16x8 av = *(const s16x8*)&hbf[rt*16 + u][k0 + g4*8];
      acc[rt][0] = MFMA16(av, b0, acc[rt][0], 0,0,0);
      acc[rt][1] = MFMA16(av, b1, acc[rt][1], 0,0,0);
      acc[rt][2] = MFMA16(av, b2, acc[rt][2], 0,0,0);
    }
  }
  int c = kt*16 + u;
  bool cv = (c < 257);
  float kmP[4] = {0.f, 0.f, 0.f, 0.f};
  #pragma unroll
  for (int rt = 0; rt < 4; ++rt) {
    int ii = rt*4 + g4;
    bool act = cv && (ii <= j);
    float h2v[4];
    #pragma unroll
    for (int r = 0; r < 4; ++r) {
      int rowl = rt*16 + g4*4 + r;
      float hp = b2f(hbf[rowl][cv ? c : 0]);
      if (act) {
        const ushort* gi = GiAll + ((size_t)(nb+r)*16 + j)*832 + 3*kt*16 + u;
        h2v[r] = gruh(b2f(gi[0]) + bih[c], b2f(gi[16]) + bih[257+c], b2f(gi[32]) + bih[514+c],
                      acc[rt][0][r] + bhh[c], acc[rt][1][r] + bhh[257+c], acc[rt][2][r] + bhh[514+c], hp);
        if (c < 256) kmP[r] += h2v[r];
        if (c == 256) Cm[(size_t)(nb+r)*256 + ii*16 + j] = h2v[r];
      } else h2v[r] = hp;
    }
    h2p[rt][0] = (unsigned)f2b(h2v[0]) | ((unsigned)f2b(h2v[1]) << 16);
    h2p[rt][1] = (unsigned)f2b(h2v[2]) | ((unsigned)f2b(h2v[3]) << 16);
  }
  if (kt < 16) {
    #pragma unroll
    for (int r = 0; r < 4; ++r) {
      float s = kmP[r];
      s += __shfl_xor(s, 16, 64);
      s += __shfl_xor(s, 32, 64);
      if (lane < 16) Km[((size_t)(nb+r)*16 + j)*256 + c] = s;
    }
  }
}
__device__ __forceinline__ void enc1b_wb(int kt, int j, int u, int g4,
    ushort hbf[64][328], const unsigned (&h2p)[4][2])
{
  int c = kt*16 + u;
  if (c < 257) {
    #pragma unroll
    for (int rt = 0; rt < 4; ++rt) {
      int ii = rt*4 + g4;
      if (ii <= j) {
        hbf[rt*16 + g4*4 + 0][c] = (ushort)(h2p[rt][0] & 0xFFFFu);
        hbf[rt*16 + g4*4 + 1][c] = (ushort)(h2p[rt][0] >> 16);
        hbf[rt*16 + g4*4 + 2][c] = (ushort)(h2p[rt][1] & 0xFFFFu);
        hbf[rt*16 + g4*4 + 3][c] = (ushort)(h2p[rt][1] >> 16);
      }
    }
  }
}
__global__ __launch_bounds__(512) void enc1b(
    const ushort* __restrict__ GiAll, const ushort* __restrict__ Wh,
    const float* __restrict__ bih, const float* __restrict__ bhh,
    float* __restrict__ Km, float* __restrict__ Cm){
  __shared__ __align__(16) ushort hbf[64][328];
  int tid = threadIdx.x, lane = tid & 63, wv = tid >> 6;
  int u = lane & 15, g4 = lane >> 4;
  int nb = blockIdx.x * 4;
  for (int i = tid; i < 64*328; i += 512) ((ushort*)hbf)[i] = 0;
  BAR();
  for (int j = 0; j < 16; ++j) {
    unsigned hA[4][2], hB[4][2], hC[4][2];
    enc1b_tile(wv,     j, nb, u, g4, lane, hbf, GiAll, Wh, bih, bhh, Km, Cm, hA);
    enc1b_tile(wv + 8, j, nb, u, g4, lane, hbf, GiAll, Wh, bih, bhh, Km, Cm, hB);
    if (wv == 0) enc1b_tile(16, j, nb, u, g4, lane, hbf, GiAll, Wh, bih, bhh, Km, Cm, hC);
    BAR();
    enc1b_wb(wv,     j, u, g4, hbf, hA);
    enc1b_wb(wv + 8, j, u, g4, hbf, hB);
    if (wv == 0) enc1b_wb(16, j, u, g4, hbf, hC);
    BAR();
  }
}

// ---------- backward-part K accumulate + C fill (i>j) ----------
__global__ void accum_bwd(const ushort* __restrict__ Bbf, float* __restrict__ Km,
                          float* __restrict__ Cm){
  int n = blockIdx.x, c = threadIdx.x;
  float s = 0.f;
  for (int jj = 15; jj >= 0; --jj) {
    if (jj < 15) s += b2f(Bbf[((size_t)(14-jj)*1024 + n)*288 + c]);
    Km[((size_t)n*16 + jj)*256 + c] += s;
  }
  int i = c >> 4, j = c & 15;
  if (i > j) Cm[(size_t)n*256 + i*16 + j] = b2f(Bbf[((size_t)(i-1-j)*1024 + n)*288 + 256]);
}
__global__ void wb_kernel(const float* __restrict__ Km, const float* __restrict__ ba,
                          float* __restrict__ wbv){
  int n = blockIdx.x, t = threadIdx.x;
  int l = t >> 4, lane = t & 15;
  float s = 0.f;
  for (int m = lane; m < 256; m += 16) s += Km[((size_t)n*16 + l)*256 + m]*ba[m];
  s += __shfl_down(s, 8, 16); s += __shfl_down(s, 4, 16);
  s += __shfl_down(s, 2, 16); s += __shfl_down(s, 1, 16);
  if (lane == 0) wbv[n*16 + l] = s;
}

// ---------- cell chunk: 16 t-steps, weight-stationary (Wh in VGPRs) ----------
// 64 blocks x 512 threads (8 waves); wave handles col-tiles kt and kt+8.
// Gi: [16][1024][768] bf16, gate-permuted, biases folded (r,z: bih+bhh; g: bih only).
__global__ __launch_bounds__(512) void cell_chunk(
    const ushort* __restrict__ Gi, const ushort* __restrict__ Wh,
    const float* __restrict__ bhh, const float* __restrict__ hbuf,
    int t0, ushort* __restrict__ hcT, float* __restrict__ out){
  __shared__ __align__(16) ushort hbf[2][16][266];   // stride 266us = 133 dwords (odd) -> low bank conflicts
  int tid = threadIdx.x, lane = tid & 63, wv = tid >> 6;  // wv 0..7
  int u = lane & 15, g4 = lane >> 4;
  int n0 = blockIdx.x * 16;
  int ktA = wv, ktB = wv + 8;
  int cA = ktA*16 + u, cB = ktB*16 + u;
  // preload all Wh fragments for both tiles: 48 x s16x8 = 192 VGPR
  s16x8 WA0[8], WA1[8], WA2[8], WB0[8], WB1[8], WB2[8];
  #pragma unroll
  for (int q = 0; q < 8; ++q) {
    int off = q*32 + g4*8;
    WA0[q] = *(const s16x8*)(Wh + (size_t)((3*ktA+0)*16 + u)*256 + off);
    WA1[q] = *(const s16x8*)(Wh + (size_t)((3*ktA+1)*16 + u)*256 + off);
    WA2[q] = *(const s16x8*)(Wh + (size_t)((3*ktA+2)*16 + u)*256 + off);
    WB0[q] = *(const s16x8*)(Wh + (size_t)((3*ktB+0)*16 + u)*256 + off);
    WB1[q] = *(const s16x8*)(Wh + (size_t)((3*ktB+1)*16 + u)*256 + off);
    WB2[q] = *(const s16x8*)(Wh + (size_t)((3*ktB+2)*16 + u)*256 + off);
  }
  float bhgA = bhh[512 + cA], bhgB = bhh[512 + cB];
  if (t0 == 0) {
    for (int i = tid; i < 16*256; i += 512) {
      int rr = i >> 8, cc = i & 255;
      hbf[0][rr][cc] = f2b(hbuf[(size_t)(n0 + rr)*256 + cc]);
    }
  } else {
    for (int i = tid; i < 16*256; i += 512) {
      int rr = i >> 8, cc = i & 255;
      hbf[0][rr][cc] = hcT[((size_t)(t0-1)*1024 + n0 + rr)*256 + cc];
    }
  }
  BAR();
  int cur = 0;
  for (int s = 0; s < 16; ++s) {
    int t = t0 + s;
    f32x4 a0={0,0,0,0},a1={0,0,0,0},a2={0,0,0,0};
    f32x4 b0={0,0,0,0},b1={0,0,0,0},b2={0,0,0,0};
    #pragma unroll
    for (int q = 0; q < 8; ++q) {
      s16x8 ah = *(const s16x8*)&hbf[cur][u][q*32 + g4*8];
      a0 = MFMA16(ah, WA0[q], a0, 0,0,0);
      a1 = MFMA16(ah, WA1[q], a1, 0,0,0);
      a2 = MFMA16(ah, WA2[q], a2, 0,0,0);
      b0 = MFMA16(ah, WB0[q], b0, 0,0,0);
      b1 = MFMA16(ah, WB1[q], b1, 0,0,0);
      b2 = MFMA16(ah, WB2[q], b2, 0,0,0);
    }
    const ushort* gbase = Gi + (size_t)s*1024*768;
    #pragma unroll
    for (int r = 0; r < 4; ++r) {
      int row = g4*4 + r;
      const ushort* gr = gbase + (size_t)(n0 + row)*768;
      // tile A
      {
        float gir = b2f(gr[3*ktA*16 + u]);
        float giz = b2f(gr[3*ktA*16 + 16 + u]);
        float gig = b2f(gr[3*ktA*16 + 32 + u]);
        float hp  = b2f(hbf[cur][row][cA]);
        float rr2 = 1.f/(1.f + __expf(-(gir + a0[r])));
        float zz  = 1.f/(1.f + __expf(-(giz + a1[r])));
        float ex  = __expf(2.f*(gig + rr2*(a2[r] + bhgA)));
        float gg  = 1.f - 2.f/(ex + 1.f);
        float h2  = (1.f - zz)*gg + zz*hp;
        ushort hb = f2b(h2);
        hbf[cur^1][row][cA] = hb;
        hcT[((size_t)t*1024 + n0 + row)*256 + cA] = hb;
        out[((size_t)t*1024 + n0 + row)*STATE_ + 2 + cA] = h2;
        if (t == 63) out[((size_t)64*1024 + n0 + row)*STATE_ + 2 + cA] = h2;
      }
      // tile B
      {
        float gir = b2f(gr[3*ktB*16 + u]);
        float giz = b2f(gr[3*ktB*16 + 16 + u]);
        float gig = b2f(gr[3*ktB*16 + 32 + u]);
        float hp  = b2f(hbf[cur][row][cB]);
        float rr2 = 1.f/(1.f + __expf(-(gir + b0[r])));
        float zz  = 1.f/(1.f + __expf(-(giz + b1[r])));
        float ex  = __expf(2.f*(gig + rr2*(b2[r] + bhgB)));
        float gg  = 1.f - 2.f/(ex + 1.f);
        float h2  = (1.f - zz)*gg + zz*hp;
        ushort hb = f2b(h2);
        hbf[cur^1][row][cB] = hb;
        hcT[((size_t)t*1024 + n0 + row)*256 + cB] = hb;
        out[((size_t)t*1024 + n0 + row)*STATE_ + 2 + cB] = h2;
        if (t == 63) out[((size_t)64*1024 + n0 + row)*STATE_ + 2 + cB] = h2;
      }
    }
    BAR();
    cur ^= 1;
  }
}

// ---------- v & a columns: one wave per output row ----------
__global__ __launch_bounds__(256) void v_out(
    const ushort* __restrict__ hcT, const int* __restrict__ act,
    const float* __restrict__ Wc, const float* __restrict__ bc,
    float* __restrict__ out){
  int rowid = blockIdx.x*4 + (threadIdx.x >> 6);
  if (rowid >= 65*1024) return;
  int lane = threadIdx.x & 63;
  int tt = rowid >> 10, n = rowid & 1023;
  int t = tt > 63 ? 63 : tt;
  us4 hv = *(const us4*)(hcT + ((size_t)t*1024 + n)*256 + lane*4);
  f32x4 wv4 = *(const f32x4*)(Wc + lane*4);
  float s = b2f(hv[0])*wv4[0] + b2f(hv[1])*wv4[1] + b2f(hv[2])*wv4[2] + b2f(hv[3])*wv4[3];
  #pragma unroll
  for (int off = 32; off > 0; off >>= 1) s += __shfl_xor(s, off, 64);
  if (lane == 0) {
    size_t ro = (size_t)rowid*STATE_;
    out[ro]     = (float)act[(size_t)t*1024 + n];
    out[ro + 1] = s + bc[0];
  }
}

// ---------- batched attention/softmax post-pass: block = n, wave = 16 t's ----------
__global__ __launch_bounds__(256) void attn_batch(
    const ushort* __restrict__ Ktl, const ushort* __restrict__ hcT,
    const float* __restrict__ wbv, const float* __restrict__ Cm,
    const float* __restrict__ p0, const int* __restrict__ act,
    float* __restrict__ out){
  int n = blockIdx.x;
  int lane = threadIdx.x & 63, wv = threadIdx.x >> 6;
  int u = lane & 15, g4 = lane >> 4;
  int t0 = wv*16;
  const ushort* Ka = Ktl + ((size_t)n*16 + u)*256 + g4*8;          // A rows = l
  const ushort* Hb = hcT + ((size_t)(t0 + u)*1024 + n)*256 + g4*8; // B rows = t ([t][n] layout)
  f32x4 acc = {0,0,0,0};
  #pragma unroll
  for (int q = 0; q < 8; ++q) {
    s16x8 av = *(const s16x8*)(Ka + q*32);
    s16x8 bv = *(const s16x8*)(Hb + q*32);
    acc = MFMA16(av, bv, acc, 0,0,0);
  }
  int t = t0 + u;
  float ps[4];
  if (t == 0) {
    #pragma unroll
    for (int r = 0; r < 4; ++r) {
      float catt = 0.f;
      for (int i = 0; i < 16; ++i) catt += p0[n*16 + i]*Cm[(size_t)n*256 + i*16 + g4*4 + r];
      ps[r] = (acc[r] + wbv[n*16 + g4*4 + r]) * catt;
    }
  } else {
    int ap = act[(size_t)(t-1)*1024 + n];
    #pragma unroll
    for (int r = 0; r < 4; ++r)
      ps[r] = (acc[r] + wbv[n*16 + g4*4 + r]) * Cm[(size_t)n*256 + ap*16 + g4*4 + r];
  }
  float mx = fmaxf(fmaxf(ps[0], ps[1]), fmaxf(ps[2], ps[3]));
  mx = fmaxf(mx, __shfl_xor(mx, 16, 64));
  mx = fmaxf(mx, __shfl_xor(mx, 32, 64));
  float e[4], se = 0.f;
  #pragma unroll
  for (int r = 0; r < 4; ++r) { e[r] = __expf(ps[r] - mx); se += e[r]; }
  se += __shfl_xor(se, 16, 64);
  se += __shfl_xor(se, 32, 64);
  float inv = 1.f/se;
  int a = act[(size_t)t*1024 + n];
  size_t ro = ((size_t)t*1024 + n)*STATE_;
  #pragma unroll
  for (int r = 0; r < 4; ++r) {
    out[ro + 258 + g4*4 + r] = e[r]*inv;
    out[ro + 274 + g4*4 + r] = (g4*4 + r == a) ? 1.f : 0.f;
  }
  if (t == 63) {
    size_t r2 = ((size_t)64*1024 + n)*STATE_;
    #pragma unroll
    for (int r = 0; r < 4; ++r) {
      out[r2 + 258 + g4*4 + r] = e[r]*inv;
      out[r2 + 274 + g4*4 + r] = (g4*4 + r == a) ? 1.f : 0.f;
    }
  }
}

extern "C" void kernel_launch(void* const* d_in, const int* in_sizes, int n_in,
                              void* d_out, int out_size, void* d_ws, size_t ws_size,
                              hipStream_t stream){
  (void)in_sizes; (void)n_in; (void)out_size; (void)ws_size;
  const float* cond  = (const float*)d_in[0];
  const int*   lines = (const int*)  d_in[1];
  const int*   act   = (const int*)  d_in[2];
  const float* hxs   = (const float*)d_in[3];
  const float* emb   = (const float*)d_in[4];
  const float* wih_e = (const float*)d_in[5];
  const float* whh_e = (const float*)d_in[6];
  const float* bih_e = (const float*)d_in[7];
  const float* bhh_e = (const float*)d_in[8];
  const float* W1    = (const float*)d_in[9];
  const float* b1    = (const float*)d_in[10];
  const float* W2    = (const float*)d_in[11];
  const float* b2    = (const float*)d_in[12];
  const float* wih_c = (const float*)d_in[13];
  const float* whh_c = (const float*)d_in[14];
  const float* bih_c = (const float*)d_in[15];
  const float* bhh_c = (const float*)d_in[16];
  const float* Wa    = (const float*)d_in[17];
  const float* ba    = (const float*)d_in[18];
  const float* Wc    = (const float*)d_in[19];
  const float* bc    = (const float*)d_in[20];
  float* out = (float*)d_out;

  // ---- workspace layout (peak ~114.45 MB; 117.6 MB proven safe in rounds 4-6) ----
  char* base = (char*)d_ws;
  ushort* Mbf    = (ushort*)(base + 0);             // [16384,256]       P0-P3
  ushort* Bbf    = (ushort*)(base + 8388608);       // [16,1024,288]     P1-P2
  float*  Km     = (float*) (base + 17825792);      // [16384,256] f32   P1-P2
  ushort* Kmbf   = (ushort*)(base + 34603008);      // [16384,256]       P2
  ushort* xcat   = (ushort*)(base + 8388608);       // [65536,320]       P3 (over Bbf/Km/Kmbf)
  ushort* x2     = (ushort*)(base + 8388608);       // [65536,256]       P3 (over xcat)
  ushort* hcT    = (ushort*)(base + 8388608);       // [64,1024,256]     P4-P5 (over x2, per-t)
  ushort* GiAll  = (ushort*)(base + 50331648);      // [16384,832]       P1
  ushort* x1     = (ushort*)(base + 50331648);      // [65536,256]       P3
  ushort* GiC0   = (ushort*)(base + 50331648);      // [16,1024,768]     P4 (over x1)
  ushort* GiC1   = (ushort*)(base + 75497472);      // [16,1024,768]     P4
  ushort* Ktl    = (ushort*)(base + 100663296);     // [16384,256]       P2-P5
  float*  Cm     = (float*) (base + 109051904);     // [1024,16,16]
  float*  hbuf   = (float*) (base + 110100480);     // [1024,256]
  float*  p0     = (float*) (base + 111149056);     // [1024,16]
  float*  r0v    = (float*) (base + 111214592);     // [1024,256]
  float*  wbv    = (float*) (base + 112263168);     // [1024,16]
  ushort* wihe_p = (ushort*)(base + 112328704);     // [832,256]
  ushort* whhe_p = (ushort*)(base + 112754688);     // [832,288]
  ushort* wihc_p = (ushort*)(base + 113233920);     // [768,256]
  ushort* whhc_p = (ushort*)(base + 113627136);     // [768,256]
  ushort* W1b    = (ushort*)(base + 114020352);     // [256,320]
  ushort* W2b    = (ushort*)(base + 114184192);     // [256,256]
  ushort* WaTb   = (ushort*)(base + 114315264);     // [256,256]
  float*  cbias  = (float*) (base + 114446336);     // [768]

  hipMemsetAsync(Bbf, 0, (size_t)16*1024*288*2, stream);

  perm_enc_w<<<832, 256, 0, stream>>>(wih_e, wihe_p, 256, 256, 832*256);
  perm_enc_w<<<936, 256, 0, stream>>>(whh_e, whhe_p, 257, 288, 832*288);
  perm_cell_w<<<768, 256, 0, stream>>>(wih_c, wihc_p);
  perm_cell_w<<<768, 256, 0, stream>>>(whh_c, whhc_p);
  cbias_k<<<3, 256, 0, stream>>>(bih_c, bhh_c, cbias);
  conv_pad_b<<<320, 256, 0, stream>>>(W1, W1b, 256, 320, 320, 256*320);
  conv_pad_b<<<256, 256, 0, stream>>>(W2, W2b, 256, 256, 256, 256*256);
  transp_b<<<256, 256, 0, stream>>>(Wa, WaTb);

  embed_b<<<16384, 256, 0, stream>>>(lines, emb, Mbf);
  init_state<<<1024, 256, 0, stream>>>(hxs, hbuf, p0);
  r0_kernel<<<1024, 256, 0, stream>>>(p0, Mbf, r0v);

  gemm_mfma<0><<<dim3(256, 13), 256, 0, stream>>>(Mbf, wihe_p, nullptr, GiAll, 256, 832);

  enc1a<<<64, 1024, 0, stream>>>(GiAll, whhe_p, bih_e, bhh_e, Bbf);
  enc1b<<<256, 512, 0, stream>>>(GiAll, whhe_p, bih_e, bhh_e, Km, Cm);
  accum_bwd<<<1024, 256, 0, stream>>>(Bbf, Km, Cm);
  wb_kernel<<<1024, 256, 0, stream>>>(Km, ba, wbv);
  km2bf<<<16384, 256, 0, stream>>>(Km, Kmbf);
  gemm_mfma<0><<<dim3(256, 4), 256, 0, stream>>>(Kmbf, WaTb, nullptr, Ktl, 256, 256);

  build_xcat<<<81920, 256, 0, stream>>>(cond, act, r0v, Mbf, xcat);
  gemm_mfma<1><<<dim3(1024, 4), 256, 0, stream>>>(xcat, W1b, b1, x1, 320, 256);
  gemm_mfma<1><<<dim3(1024, 4), 256, 0, stream>>>(x1, W2b, b2, x2, 256, 256);

  // gi precompute chunks (ping-pong) + weight-stationary cell chunks
  ushort* gic[2] = {GiC0, GiC1};
  gemm_mfma<0><<<dim3(256, 12), 256, 0, stream>>>(x2 + (size_t)0*16384*256, wihc_p, cbias, gic[0], 256, 768);
  gemm_mfma<0><<<dim3(256, 12), 256, 0, stream>>>(x2 + (size_t)1*16384*256, wihc_p, cbias, gic[1], 256, 768);
  cell_chunk<<<64, 512, 0, stream>>>(gic[0], whhc_p, bhh_c, hbuf,  0, hcT, out);
  gemm_mfma<0><<<dim3(256, 12), 256, 0, stream>>>(x2 + (size_t)2*16384*256, wihc_p, cbias, gic[0], 256, 768);
  cell_chunk<<<64, 512, 0, stream>>>(gic[1], whhc_p, bhh_c, hbuf, 16, hcT, out);
  gemm_mfma<0><<<dim3(256, 12), 256, 0, stream>>>(x2 + (size_t)3*16384*256, wihc_p, cbias, gic[1], 256, 768);
  cell_chunk<<<64, 512, 0, stream>>>(gic[0], whhc_p, bhh_c, hbuf, 32, hcT, out);
  cell_chunk<<<64, 512, 0, stream>>>(gic[1], whhc_p, bhh_c, hbuf, 48, hcT, out);

  v_out<<<16640, 256, 0, stream>>>(hcT, act, Wc, bc, out);
  attn_batch<<<1024, 256, 0, stream>>>(Ktl, hcT, wbv, Cm, p0, act, out);
}

// Round 8
// 1803.640 us; speedup vs baseline: 5.1317x; 1.0205x over previous
//
#include <hip/hip_runtime.h>
#include <hip/hip_bf16.h>
#include <cstddef>

#define T_ 64
#define N_ 1024
#define L_ 16
#define H_ 256
#define STATE_ 290
#define KSTR 312   // hbf row stride (ushorts): 624B = 39*16 (b128-aligned), 2-way banks max

typedef short s16x8 __attribute__((ext_vector_type(8)));
typedef float f32x4 __attribute__((ext_vector_type(4)));
typedef ushort us4 __attribute__((ext_vector_type(4)));
typedef ushort us8 __attribute__((ext_vector_type(8)));
#define MFMA16 __builtin_amdgcn_mfma_f32_16x16x32_bf16

// raw barrier: wait LDS ops only, do NOT drain global stores.
#define BAR() asm volatile("s_waitcnt lgkmcnt(0)\n\ts_barrier" ::: "memory")

__device__ __forceinline__ float b2f(ushort u){ return __uint_as_float(((unsigned)u) << 16); }
__device__ __forceinline__ ushort f2b(float f){
  unsigned x = __float_as_uint(f);
  return (ushort)((x + 0x7FFFu + ((x >> 16) & 1u)) >> 16);
}
__device__ __forceinline__ float gruh(float gir,float giz,float gig,
                                      float ghr,float ghz,float ghg,float hp){
  float r = 1.f/(1.f + __expf(-(gir + ghr)));
  float z = 1.f/(1.f + __expf(-(giz + ghz)));
  float g = tanhf(gig + r*ghg);
  return (1.f - z)*g + z*hp;
}

// ---------- conversion / prep kernels ----------
__global__ void conv_pad_b(const float* __restrict__ src, ushort* __restrict__ dst,
                           int R, int C, int Cp, int total){
  int idx = blockIdx.x*256 + threadIdx.x;
  if (idx >= total) return;
  int r = idx / Cp, c = idx - r*Cp;
  dst[idx] = (r < R && c < C) ? f2b(src[(size_t)r*C + c]) : (ushort)0;
}
__global__ void perm_enc_w(const float* __restrict__ src, ushort* __restrict__ dst,
                           int Ci, int Cp, int total){
  int idx = blockIdx.x*256 + threadIdx.x;
  if (idx >= total) return;
  int d = idx / Cp, c = idx - d*Cp;
  int tile = d >> 4, u = d & 15;
  int k = tile / 3, p = tile - 3*k;
  int hc = k*16 + u;
  bool ok = (tile < 51) && (hc < 257) && (c < Ci);
  dst[idx] = ok ? f2b(src[(size_t)(p*257 + hc)*Ci + c]) : (ushort)0;
}
__global__ void perm_cell_w(const float* __restrict__ src, ushort* __restrict__ dst){
  int idx = blockIdx.x*256 + threadIdx.x;
  if (idx >= 768*256) return;
  int d = idx >> 8, c = idx & 255;
  int tile = d >> 4, u = d & 15;
  int k = tile / 3, p = tile - 3*k;
  dst[idx] = f2b(src[(size_t)(p*256 + k*16 + u)*256 + c]);
}
__global__ void cbias_k(const float* __restrict__ bih, const float* __restrict__ bhh,
                        float* __restrict__ cb){
  int d = blockIdx.x*256 + threadIdx.x;
  if (d >= 768) return;
  int tile = d >> 4, u = d & 15;
  int k = tile / 3, p = tile - 3*k;
  int src = p*256 + k*16 + u;
  cb[d] = bih[src] + (p < 2 ? bhh[src] : 0.f);
}
__global__ void transp_b(const float* __restrict__ Wa, ushort* __restrict__ WaTb){
  int m = blockIdx.x, h = threadIdx.x;
  WaTb[(size_t)h*256 + m] = f2b(Wa[(size_t)m*256 + h]);
}
__global__ void embed_b(const int* __restrict__ lines, const float* __restrict__ emb,
                        ushort* __restrict__ Mbf){
  size_t idx = (size_t)blockIdx.x*256 + threadIdx.x;
  if (idx >= (size_t)N_*L_*H_) return;
  int c = idx & 255; size_t nl = idx >> 8;
  Mbf[idx] = f2b(emb[(size_t)lines[nl]*256 + c]);
}
__global__ void init_state(const float* __restrict__ hxs, float* __restrict__ hbuf,
                           float* __restrict__ p0){
  int n = blockIdx.x, t = threadIdx.x;
  __shared__ int nz;
  if (t == 0) nz = 0;
  __syncthreads();
  for (int c = t; c < STATE_; c += 256)
    if (hxs[(size_t)n*STATE_ + c] != 0.f) atomicOr(&nz, 1);
  __syncthreads();
  bool new_ep = (nz == 0);
  for (int c = t; c < H_; c += 256) hbuf[(size_t)n*H_ + c] = hxs[(size_t)n*STATE_ + 2 + c];
  if (t < L_) {
    float pv = hxs[(size_t)n*STATE_ + 2 + H_ + L_ + t];
    if (t == 0 && new_ep) pv = 1.f;
    p0[n*L_ + t] = pv;
  }
}
__global__ void r0_kernel(const float* __restrict__ p0, const ushort* __restrict__ Mbf,
                          float* __restrict__ r0v){
  int n = blockIdx.x, c = threadIdx.x;
  float s = 0.f;
  for (int l = 0; l < 16; ++l) s += p0[n*16 + l]*b2f(Mbf[((size_t)n*16 + l)*256 + c]);
  r0v[(size_t)n*256 + c] = s;
}
// vectorized x8 build of xcat [T*N, 320]
__global__ void build_xcat8(const float* __restrict__ cond, const int* __restrict__ act,
                            const float* __restrict__ r0v, const ushort* __restrict__ Mbf,
                            ushort* __restrict__ xcat){
  int idx = blockIdx.x*256 + threadIdx.x;     // T*N*40 = 2,621,440 chunks
  if (idx >= T_*N_*40) return;
  int kc = idx % 40;
  int row = idx / 40;
  int n = row & 1023, t = row >> 10;
  us8 v;
  if (kc < 8) {
    const float* cp = cond + (size_t)row*64 + kc*8;
    #pragma unroll
    for (int i = 0; i < 8; ++i) v[i] = f2b(cp[i]);
  } else if (t == 0) {
    const float* rp = r0v + (size_t)n*256 + (kc-8)*8;
    #pragma unroll
    for (int i = 0; i < 8; ++i) v[i] = f2b(rp[i]);
  } else {
    int a = act[(size_t)(t-1)*1024 + n];
    v = *(const us8*)(Mbf + ((size_t)n*16 + a)*256 + (kc-8)*8);
  }
  *(us8*)(xcat + (size_t)idx*8) = v;
}

// ---------- MFMA GEMM: out[r,col] = act(sum_k A[r,k]*W[col,k] + bias[col]), bf16 out ----------
template<int RELU>
__global__ __launch_bounds__(256) void gemm_mfma(
    const ushort* __restrict__ A, const ushort* __restrict__ W,
    const float* __restrict__ bias, ushort* __restrict__ out,
    int Kd, int ldo){
  int lane = threadIdx.x & 63, wv = threadIdx.x >> 6;
  int u = lane & 15, g4 = lane >> 4;
  int br = blockIdx.x*64 + wv*16;
  int bm = blockIdx.y*64;
  const ushort* Arow = A + (size_t)(br + u)*Kd + g4*8;
  f32x4 acc0 = {0,0,0,0}, acc1 = {0,0,0,0}, acc2 = {0,0,0,0}, acc3 = {0,0,0,0};
  for (int k0 = 0; k0 < Kd; k0 += 32) {
    s16x8 av = *(const s16x8*)(Arow + k0);
    s16x8 b0 = *(const s16x8*)(W + (size_t)(bm +  0 + u)*Kd + k0 + g4*8);
    s16x8 b1 = *(const s16x8*)(W + (size_t)(bm + 16 + u)*Kd + k0 + g4*8);
    s16x8 b2 = *(const s16x8*)(W + (size_t)(bm + 32 + u)*Kd + k0 + g4*8);
    s16x8 b3 = *(const s16x8*)(W + (size_t)(bm + 48 + u)*Kd + k0 + g4*8);
    acc0 = MFMA16(av, b0, acc0, 0,0,0);
    acc1 = MFMA16(av, b1, acc1, 0,0,0);
    acc2 = MFMA16(av, b2, acc2, 0,0,0);
    acc3 = MFMA16(av, b3, acc3, 0,0,0);
  }
  f32x4 ac[4] = {acc0, acc1, acc2, acc3};
  #pragma unroll
  for (int mt = 0; mt < 4; ++mt) {
    int col = bm + mt*16 + u;
    float b = bias ? bias[col] : 0.f;
    #pragma unroll
    for (int r = 0; r < 4; ++r) {
      float v = ac[mt][r] + b;
      if (RELU) v = fmaxf(v, 0.f);
      out[(size_t)(br + g4*4 + r)*ldo + col] = f2b(v);
    }
  }
}

// ---------- backward encoder (unchanged structure) ----------
__device__ __forceinline__ void enc1a_tile(int kt, int l, int step, int n0, int u, int g4,
    const ushort hbf[16][328], const ushort* __restrict__ GiAll, const ushort* __restrict__ Wh,
    const float* __restrict__ bih, const float* __restrict__ bhh,
    ushort* __restrict__ Bbf, float (&h2s)[4])
{
  f32x4 a0 = {0,0,0,0}, a1 = {0,0,0,0}, a2 = {0,0,0,0};
  #pragma unroll
  for (int q = 0; q < 9; ++q) {
    int k0 = q*32;
    s16x8 av = *(const s16x8*)&hbf[u][k0 + g4*8];
    s16x8 b0 = *(const s16x8*)(Wh + (size_t)((3*kt+0)*16 + u)*288 + k0 + g4*8);
    s16x8 b1 = *(const s16x8*)(Wh + (size_t)((3*kt+1)*16 + u)*288 + k0 + g4*8);
    s16x8 b2 = *(const s16x8*)(Wh + (size_t)((3*kt+2)*16 + u)*288 + k0 + g4*8);
    a0 = MFMA16(av, b0, a0, 0,0,0);
    a1 = MFMA16(av, b1, a1, 0,0,0);
    a2 = MFMA16(av, b2, a2, 0,0,0);
  }
  int c = kt*16 + u;
  bool cv = (c < 257);
  #pragma unroll
  for (int r = 0; r < 4; ++r) {
    int row = g4*4 + r;
    float hp = b2f(hbf[row][cv ? c : 0]);
    float h2 = hp;
    if (cv) {
      const ushort* gi = GiAll + ((size_t)(n0+row)*16 + l)*832 + 3*kt*16 + u;
      h2 = gruh(b2f(gi[0]) + bih[c], b2f(gi[16]) + bih[257+c], b2f(gi[32]) + bih[514+c],
                a0[r] + bhh[c], a1[r] + bhh[257+c], a2[r] + bhh[514+c], hp);
      Bbf[((size_t)step*1024 + n0 + row)*288 + c] = f2b(h2);
    }
    h2s[r] = h2;
  }
}
__global__ __launch_bounds__(1024) void enc1a(
    const ushort* __restrict__ GiAll, const ushort* __restrict__ Wh,
    const float* __restrict__ bih, const float* __restrict__ bhh,
    ushort* __restrict__ Bbf){
  __shared__ __align__(16) ushort hbf[16][328];
  int tid = threadIdx.x, wv = tid >> 6;
  int lane = tid & 63;
  int u = lane & 15, g4 = lane >> 4;
  int n0 = blockIdx.x * 16;
  for (int i = tid; i < 16*328; i += 1024) ((ushort*)hbf)[i] = 0;
  BAR();
  for (int step = 0; step < 16; ++step) {
    int l = 15 - step;
    float hA[4], hB[4];
    enc1a_tile(wv, l, step, n0, u, g4, hbf, GiAll, Wh, bih, bhh, Bbf, hA);
    if (wv == 0) enc1a_tile(16, l, step, n0, u, g4, hbf, GiAll, Wh, bih, bhh, Bbf, hB);
    BAR();
    {
      int c = wv*16 + u;
      #pragma unroll
      for (int r = 0; r < 4; ++r) hbf[g4*4 + r][c] = f2b(hA[r]);
      if (wv == 0 && u == 0) {
        #pragma unroll
        for (int r = 0; r < 4; ++r) hbf[g4*4 + r][256] = f2b(hB[r]);
      }
    }
    BAR();
  }
}

// ---------- forward triangular encoder v2: spill-free partition ----------
// 256 blocks x 1024 threads (16 waves). wave = (rt = w&3 row-tile, cg = w>>2 col-group).
// Double-buffered hbf + double-buffered kmS -> 1 lgkm barrier per j, no cross-barrier regs.
__device__ __forceinline__ void enc1b_proc(
    int kt, int j, int nb, int rt, int u, int g4, int iB, int cur,
    const s16x8 (&av)[9],
    ushort hbf[2][64][KSTR], float kmS[2][4][4][256],
    const ushort* __restrict__ GiAll, const ushort* __restrict__ Wh,
    const float* __restrict__ bih, const float* __restrict__ bhh,
    float* __restrict__ Cm)
{
  f32x4 a0 = {0,0,0,0}, a1 = {0,0,0,0}, a2 = {0,0,0,0};
  #pragma unroll
  for (int q = 0; q < 9; ++q) {
    int off = q*32 + g4*8;
    s16x8 b0 = *(const s16x8*)(Wh + (size_t)((3*kt+0)*16 + u)*288 + off);
    s16x8 b1 = *(const s16x8*)(Wh + (size_t)((3*kt+1)*16 + u)*288 + off);
    s16x8 b2 = *(const s16x8*)(Wh + (size_t)((3*kt+2)*16 + u)*288 + off);
    a0 = MFMA16(av[q], b0, a0, 0,0,0);
    a1 = MFMA16(av[q], b1, a1, 0,0,0);
    a2 = MFMA16(av[q], b2, a2, 0,0,0);
  }
  int c = kt*16 + u;
  bool cv = (c < 257);
  bool act = cv && (iB <= j);
  float kmP[4];
  #pragma unroll
  for (int r = 0; r < 4; ++r) {
    int rowl = rt*16 + g4*4 + r;
    float h2 = 0.f;
    if (act) {
      const ushort* gi = GiAll + ((size_t)(nb+r)*16 + j)*832 + 3*kt*16 + u;
      float hp = b2f(hbf[cur][rowl][c]);
      h2 = gruh(b2f(gi[0]) + bih[c], b2f(gi[16]) + bih[257+c], b2f(gi[32]) + bih[514+c],
                a0[r] + bhh[c], a1[r] + bhh[257+c], a2[r] + bhh[514+c], hp);
      hbf[cur^1][rowl][c] = f2b(h2);
      if (c == 256) Cm[(size_t)(nb+r)*256 + iB*16 + j] = h2;
    }
    kmP[r] = (act && c < 256) ? h2 : 0.f;
  }
  if (kt < 16) {
    #pragma unroll
    for (int r = 0; r < 4; ++r) {
      float s = kmP[r];
      s += __shfl_xor(s, 16, 64);
      s += __shfl_xor(s, 32, 64);
      if (g4 == 0) kmS[j & 1][rt][r][c] = s;
    }
  }
}
__global__ __launch_bounds__(1024) void enc1b(
    const ushort* __restrict__ GiAll, const ushort* __restrict__ Wh,
    const float* __restrict__ bih, const float* __restrict__ bhh,
    float* __restrict__ Km, float* __restrict__ Cm){
  __shared__ __align__(16) ushort hbf[2][64][KSTR];   // 79,872 B
  __shared__ float kmS[2][4][4][256];                 // 32,768 B
  int tid = threadIdx.x, lane = tid & 63, wv = tid >> 6;
  int u = lane & 15, g4 = lane >> 4;
  int rt = wv & 3, cg = wv >> 2;
  int nb = blockIdx.x * 4;
  int iB = rt*4 + g4;
  for (int i = tid; i < 2*64*KSTR; i += 1024) ((ushort*)hbf)[i] = 0;
  BAR();
  for (int j = 0; j < 16; ++j) {
    int cur = j & 1;
    if (4*rt <= j) {
      s16x8 av[9];
      #pragma unroll
      for (int q = 0; q < 9; ++q) av[q] = *(const s16x8*)&hbf[cur][rt*16 + u][q*32 + g4*8];
      #pragma unroll
      for (int m = 0; m < 4; ++m)
        enc1b_proc(cg*4 + m, j, nb, rt, u, g4, iB, cur, av, hbf, kmS, GiAll, Wh, bih, bhh, Cm);
      if (cg == 0)
        enc1b_proc(16, j, nb, rt, u, g4, iB, cur, av, hbf, kmS, GiAll, Wh, bih, bhh, Cm);
    } else if (g4 == 0) {
      #pragma unroll
      for (int m = 0; m < 4; ++m) {
        int c = (cg*4 + m)*16 + u;
        kmS[cur][rt][0][c] = 0.f; kmS[cur][rt][1][c] = 0.f;
        kmS[cur][rt][2][c] = 0.f; kmS[cur][rt][3][c] = 0.f;
      }
    }
    BAR();
    {
      int nl = tid >> 8, c = tid & 255;
      Km[((size_t)(nb+nl)*16 + j)*256 + c] =
        kmS[cur][0][nl][c] + kmS[cur][1][nl][c] + kmS[cur][2][nl][c] + kmS[cur][3][nl][c];
    }
  }
}

// ---------- backward-part K accumulate + bf16 copy + C fill (i>j) ----------
__global__ void accum_bwd(const ushort* __restrict__ Bbf, float* __restrict__ Km,
                          ushort* __restrict__ Kmbf, float* __restrict__ Cm){
  int n = blockIdx.x, c = threadIdx.x;
  float s = 0.f;
  for (int jj = 15; jj >= 0; --jj) {
    if (jj < 15) s += b2f(Bbf[((size_t)(14-jj)*1024 + n)*288 + c]);
    size_t o = ((size_t)n*16 + jj)*256 + c;
    float v = Km[o] + s;
    Km[o] = v;
    Kmbf[o] = f2b(v);
  }
  int i = c >> 4, j = c & 15;
  if (i > j) Cm[(size_t)n*256 + i*16 + j] = b2f(Bbf[((size_t)(i-1-j)*1024 + n)*288 + 256]);
}
__global__ void wb_kernel(const float* __restrict__ Km, const float* __restrict__ ba,
                          float* __restrict__ wbv){
  int n = blockIdx.x, t = threadIdx.x;
  int l = t >> 4, lane = t & 15;
  float s = 0.f;
  for (int m = lane; m < 256; m += 16) s += Km[((size_t)n*16 + l)*256 + m]*ba[m];
  s += __shfl_down(s, 8, 16); s += __shfl_down(s, 4, 16);
  s += __shfl_down(s, 2, 16); s += __shfl_down(s, 1, 16);
  if (lane == 0) wbv[n*16 + l] = s;
}

// ---------- cell chunk: 16 t-steps, weight-stationary (Wh in VGPRs) ----------
__global__ __launch_bounds__(512) void cell_chunk(
    const ushort* __restrict__ Gi, const ushort* __restrict__ Wh,
    const float* __restrict__ bhh, const float* __restrict__ hbuf,
    int t0, ushort* __restrict__ hcT, float* __restrict__ out){
  __shared__ __align__(16) ushort hbf[2][16][266];
  int tid = threadIdx.x, lane = tid & 63, wv = tid >> 6;
  int u = lane & 15, g4 = lane >> 4;
  int n0 = blockIdx.x * 16;
  int ktA = wv, ktB = wv + 8;
  int cA = ktA*16 + u, cB = ktB*16 + u;
  s16x8 WA0[8], WA1[8], WA2[8], WB0[8], WB1[8], WB2[8];
  #pragma unroll
  for (int q = 0; q < 8; ++q) {
    int off = q*32 + g4*8;
    WA0[q] = *(const s16x8*)(Wh + (size_t)((3*ktA+0)*16 + u)*256 + off);
    WA1[q] = *(const s16x8*)(Wh + (size_t)((3*ktA+1)*16 + u)*256 + off);
    WA2[q] = *(const s16x8*)(Wh + (size_t)((3*ktA+2)*16 + u)*256 + off);
    WB0[q] = *(const s16x8*)(Wh + (size_t)((3*ktB+0)*16 + u)*256 + off);
    WB1[q] = *(const s16x8*)(Wh + (size_t)((3*ktB+1)*16 + u)*256 + off);
    WB2[q] = *(const s16x8*)(Wh + (size_t)((3*ktB+2)*16 + u)*256 + off);
  }
  float bhgA = bhh[512 + cA], bhgB = bhh[512 + cB];
  if (t0 == 0) {
    for (int i = tid; i < 16*256; i += 512) {
      int rr = i >> 8, cc = i & 255;
      hbf[0][rr][cc] = f2b(hbuf[(size_t)(n0 + rr)*256 + cc]);
    }
  } else {
    for (int i = tid; i < 16*256; i += 512) {
      int rr = i >> 8, cc = i & 255;
      hbf[0][rr][cc] = hcT[((size_t)(t0-1)*1024 + n0 + rr)*256 + cc];
    }
  }
  BAR();
  int cur = 0;
  for (int s = 0; s < 16; ++s) {
    int t = t0 + s;
    f32x4 a0={0,0,0,0},a1={0,0,0,0},a2={0,0,0,0};
    f32x4 b0={0,0,0,0},b1={0,0,0,0},b2={0,0,0,0};
    #pragma unroll
    for (int q = 0; q < 8; ++q) {
      s16x8 ah = *(const s16x8*)&hbf[cur][u][q*32 + g4*8];
      a0 = MFMA16(ah, WA0[q], a0, 0,0,0);
      a1 = MFMA16(ah, WA1[q], a1, 0,0,0);
      a2 = MFMA16(ah, WA2[q], a2, 0,0,0);
      b0 = MFMA16(ah, WB0[q], b0, 0,0,0);
      b1 = MFMA16(ah, WB1[q], b1, 0,0,0);
      b2 = MFMA16(ah, WB2[q], b2, 0,0,0);
    }
    const ushort* gbase = Gi + (size_t)s*1024*768;
    #pragma unroll
    for (int r = 0; r < 4; ++r) {
      int row = g4*4 + r;
      const ushort* gr = gbase + (size_t)(n0 + row)*768;
      {
        float gir = b2f(gr[3*ktA*16 + u]);
        float giz = b2f(gr[3*ktA*16 + 16 + u]);
        float gig = b2f(gr[3*ktA*16 + 32 + u]);
        float hp  = b2f(hbf[cur][row][cA]);
        float rr2 = 1.f/(1.f + __expf(-(gir + a0[r])));
        float zz  = 1.f/(1.f + __expf(-(giz + a1[r])));
        float ex  = __expf(2.f*(gig + rr2*(a2[r] + bhgA)));
        float gg  = 1.f - 2.f/(ex + 1.f);
        float h2  = (1.f - zz)*gg + zz*hp;
        ushort hb = f2b(h2);
        hbf[cur^1][row][cA] = hb;
        hcT[((size_t)t*1024 + n0 + row)*256 + cA] = hb;
        out[((size_t)t*1024 + n0 + row)*STATE_ + 2 + cA] = h2;
        if (t == 63) out[((size_t)64*1024 + n0 + row)*STATE_ + 2 + cA] = h2;
      }
      {
        float gir = b2f(gr[3*ktB*16 + u]);
        float giz = b2f(gr[3*ktB*16 + 16 + u]);
        float gig = b2f(gr[3*ktB*16 + 32 + u]);
        float hp  = b2f(hbf[cur][row][cB]);
        float rr2 = 1.f/(1.f + __expf(-(gir + b0[r])));
        float zz  = 1.f/(1.f + __expf(-(giz + b1[r])));
        float ex  = __expf(2.f*(gig + rr2*(b2[r] + bhgB)));
        float gg  = 1.f - 2.f/(ex + 1.f);
        float h2  = (1.f - zz)*gg + zz*hp;
        ushort hb = f2b(h2);
        hbf[cur^1][row][cB] = hb;
        hcT[((size_t)t*1024 + n0 + row)*256 + cB] = hb;
        out[((size_t)t*1024 + n0 + row)*STATE_ + 2 + cB] = h2;
        if (t == 63) out[((size_t)64*1024 + n0 + row)*STATE_ + 2 + cB] = h2;
      }
    }
    BAR();
    cur ^= 1;
  }
}

// ---------- v & a columns: one wave per output row ----------
__global__ __launch_bounds__(256) void v_out(
    const ushort* __restrict__ hcT, const int* __restrict__ act,
    const float* __restrict__ Wc, const float* __restrict__ bc,
    float* __restrict__ out){
  int rowid = blockIdx.x*4 + (threadIdx.x >> 6);
  if (rowid >= 65*1024) return;
  int lane = threadIdx.x & 63;
  int tt = rowid >> 10, n = rowid & 1023;
  int t = tt > 63 ? 63 : tt;
  us4 hv = *(const us4*)(hcT + ((size_t)t*1024 + n)*256 + lane*4);
  f32x4 wv4 = *(const f32x4*)(Wc + lane*4);
  float s = b2f(hv[0])*wv4[0] + b2f(hv[1])*wv4[1] + b2f(hv[2])*wv4[2] + b2f(hv[3])*wv4[3];
  #pragma unroll
  for (int off = 32; off > 0; off >>= 1) s += __shfl_xor(s, off, 64);
  if (lane == 0) {
    size_t ro = (size_t)rowid*STATE_;
    out[ro]     = (float)act[(size_t)t*1024 + n];
    out[ro + 1] = s + bc[0];
  }
}

// ---------- batched attention/softmax post-pass ----------
__global__ __launch_bounds__(256) void attn_batch(
    const ushort* __restrict__ Ktl, const ushort* __restrict__ hcT,
    const float* __restrict__ wbv, const float* __restrict__ Cm,
    const float* __restrict__ p0, const int* __restrict__ act,
    float* __restrict__ out){
  int n = blockIdx.x;
  int lane = threadIdx.x & 63, wv = threadIdx.x >> 6;
  int u = lane & 15, g4 = lane >> 4;
  int t0 = wv*16;
  const ushort* Ka = Ktl + ((size_t)n*16 + u)*256 + g4*8;
  const ushort* Hb = hcT + ((size_t)(t0 + u)*1024 + n)*256 + g4*8;
  f32x4 acc = {0,0,0,0};
  #pragma unroll
  for (int q = 0; q < 8; ++q) {
    s16x8 av = *(const s16x8*)(Ka + q*32);
    s16x8 bv = *(const s16x8*)(Hb + q*32);
    acc = MFMA16(av, bv, acc, 0,0,0);
  }
  int t = t0 + u;
  float ps[4];
  if (t == 0) {
    #pragma unroll
    for (int r = 0; r < 4; ++r) {
      float catt = 0.f;
      for (int i = 0; i < 16; ++i) catt += p0[n*16 + i]*Cm[(size_t)n*256 + i*16 + g4*4 + r];
      ps[r] = (acc[r] + wbv[n*16 + g4*4 + r]) * catt;
    }
  } else {
    int ap = act[(size_t)(t-1)*1024 + n];
    #pragma unroll
    for (int r = 0; r < 4; ++r)
      ps[r] = (acc[r] + wbv[n*16 + g4*4 + r]) * Cm[(size_t)n*256 + ap*16 + g4*4 + r];
  }
  float mx = fmaxf(fmaxf(ps[0], ps[1]), fmaxf(ps[2], ps[3]));
  mx = fmaxf(mx, __shfl_xor(mx, 16, 64));
  mx = fmaxf(mx, __shfl_xor(mx, 32, 64));
  float e[4], se = 0.f;
  #pragma unroll
  for (int r = 0; r < 4; ++r) { e[r] = __expf(ps[r] - mx); se += e[r]; }
  se += __shfl_xor(se, 16, 64);
  se += __shfl_xor(se, 32, 64);
  float inv = 1.f/se;
  int a = act[(size_t)t*1024 + n];
  size_t ro = ((size_t)t*1024 + n)*STATE_;
  #pragma unroll
  for (int r = 0; r < 4; ++r) {
    out[ro + 258 + g4*4 + r] = e[r]*inv;
    out[ro + 274 + g4*4 + r] = (g4*4 + r == a) ? 1.f : 0.f;
  }
  if (t == 63) {
    size_t r2 = ((size_t)64*1024 + n)*STATE_;
    #pragma unroll
    for (int r = 0; r < 4; ++r) {
      out[r2 + 258 + g4*4 + r] = e[r]*inv;
      out[r2 + 274 + g4*4 + r] = (g4*4 + r == a) ? 1.f : 0.f;
    }
  }
}

extern "C" void kernel_launch(void* const* d_in, const int* in_sizes, int n_in,
                              void* d_out, int out_size, void* d_ws, size_t ws_size,
                              hipStream_t stream){
  (void)in_sizes; (void)n_in; (void)out_size; (void)ws_size;
  const float* cond  = (const float*)d_in[0];
  const int*   lines = (const int*)  d_in[1];
  const int*   act   = (const int*)  d_in[2];
  const float* hxs   = (const float*)d_in[3];
  const float* emb   = (const float*)d_in[4];
  const float* wih_e = (const float*)d_in[5];
  const float* whh_e = (const float*)d_in[6];
  const float* bih_e = (const float*)d_in[7];
  const float* bhh_e = (const float*)d_in[8];
  const float* W1    = (const float*)d_in[9];
  const float* b1    = (const float*)d_in[10];
  const float* W2    = (const float*)d_in[11];
  const float* b2    = (const float*)d_in[12];
  const float* wih_c = (const float*)d_in[13];
  const float* whh_c = (const float*)d_in[14];
  const float* bih_c = (const float*)d_in[15];
  const float* bhh_c = (const float*)d_in[16];
  const float* Wa    = (const float*)d_in[17];
  const float* ba    = (const float*)d_in[18];
  const float* Wc    = (const float*)d_in[19];
  const float* bc    = (const float*)d_in[20];
  float* out = (float*)d_out;

  char* base = (char*)d_ws;
  ushort* Mbf    = (ushort*)(base + 0);             // [16384,256]       P0-P3
  ushort* Bbf    = (ushort*)(base + 8388608);       // [16,1024,288]     P1-P2
  float*  Km     = (float*) (base + 17825792);      // [16384,256] f32   P1-P2
  ushort* Kmbf   = (ushort*)(base + 34603008);      // [16384,256]       P2
  ushort* xcat   = (ushort*)(base + 8388608);       // [65536,320]       P3
  ushort* x2     = (ushort*)(base + 8388608);       // [65536,256]       P3
  ushort* hcT    = (ushort*)(base + 8388608);       // [64,1024,256]     P4-P5
  ushort* GiAll  = (ushort*)(base + 50331648);      // [16384,832]       P1
  ushort* x1     = (ushort*)(base + 50331648);      // [65536,256]       P3
  ushort* GiC0   = (ushort*)(base + 50331648);      // [16,1024,768]     P4
  ushort* GiC1   = (ushort*)(base + 75497472);      // [16,1024,768]     P4
  ushort* Ktl    = (ushort*)(base + 100663296);     // [16384,256]       P2-P5
  float*  Cm     = (float*) (base + 109051904);     // [1024,16,16]
  float*  hbuf   = (float*) (base + 110100480);     // [1024,256]
  float*  p0     = (float*) (base + 111149056);     // [1024,16]
  float*  r0v    = (float*) (base + 111214592);     // [1024,256]
  float*  wbv    = (float*) (base + 112263168);     // [1024,16]
  ushort* wihe_p = (ushort*)(base + 112328704);     // [832,256]
  ushort* whhe_p = (ushort*)(base + 112754688);     // [832,288]
  ushort* wihc_p = (ushort*)(base + 113233920);     // [768,256]
  ushort* whhc_p = (ushort*)(base + 113627136);     // [768,256]
  ushort* W1b    = (ushort*)(base + 114020352);     // [256,320]
  ushort* W2b    = (ushort*)(base + 114184192);     // [256,256]
  ushort* WaTb   = (ushort*)(base + 114315264);     // [256,256]
  float*  cbias  = (float*) (base + 114446336);     // [768]

  hipMemsetAsync(Bbf, 0, (size_t)16*1024*288*2, stream);

  perm_enc_w<<<832, 256, 0, stream>>>(wih_e, wihe_p, 256, 256, 832*256);
  perm_enc_w<<<936, 256, 0, stream>>>(whh_e, whhe_p, 257, 288, 832*288);
  perm_cell_w<<<768, 256, 0, stream>>>(wih_c, wihc_p);
  perm_cell_w<<<768, 256, 0, stream>>>(whh_c, whhc_p);
  cbias_k<<<3, 256, 0, stream>>>(bih_c, bhh_c, cbias);
  conv_pad_b<<<320, 256, 0, stream>>>(W1, W1b, 256, 320, 320, 256*320);
  conv_pad_b<<<256, 256, 0, stream>>>(W2, W2b, 256, 256, 256, 256*256);
  transp_b<<<256, 256, 0, stream>>>(Wa, WaTb);

  embed_b<<<16384, 256, 0, stream>>>(lines, emb, Mbf);
  init_state<<<1024, 256, 0, stream>>>(hxs, hbuf, p0);
  r0_kernel<<<1024, 256, 0, stream>>>(p0, Mbf, r0v);

  gemm_mfma<0><<<dim3(256, 13), 256, 0, stream>>>(Mbf, wihe_p, nullptr, GiAll, 256, 832);

  enc1a<<<64, 1024, 0, stream>>>(GiAll, whhe_p, bih_e, bhh_e, Bbf);
  enc1b<<<256, 1024, 0, stream>>>(GiAll, whhe_p, bih_e, bhh_e, Km, Cm);
  accum_bwd<<<1024, 256, 0, stream>>>(Bbf, Km, Kmbf, Cm);
  wb_kernel<<<1024, 256, 0, stream>>>(Km, ba, wbv);
  gemm_mfma<0><<<dim3(256, 4), 256, 0, stream>>>(Kmbf, WaTb, nullptr, Ktl, 256, 256);

  build_xcat8<<<10240, 256, 0, stream>>>(cond, act, r0v, Mbf, xcat);
  gemm_mfma<1><<<dim3(1024, 4), 256, 0, stream>>>(xcat, W1b, b1, x1, 320, 256);
  gemm_mfma<1><<<dim3(1024, 4), 256, 0, stream>>>(x1, W2b, b2, x2, 256, 256);

  ushort* gic[2] = {GiC0, GiC1};
  gemm_mfma<0><<<dim3(256, 12), 256, 0, stream>>>(x2 + (size_t)0*16384*256, wihc_p, cbias, gic[0], 256, 768);
  gemm_mfma<0><<<dim3(256, 12), 256, 0, stream>>>(x2 + (size_t)1*16384*256, wihc_p, cbias, gic[1], 256, 768);
  cell_chunk<<<64, 512, 0, stream>>>(gic[0], whhc_p, bhh_c, hbuf,  0, hcT, out);
  gemm_mfma<0><<<dim3(256, 12), 256, 0, stream>>>(x2 + (size_t)2*16384*256, wihc_p, cbias, gic[0], 256, 768);
  cell_chunk<<<64, 512, 0, stream>>>(gic[1], whhc_p, bhh_c, hbuf, 16, hcT, out);
  gemm_mfma<0><<<dim3(256, 12), 256, 0, stream>>>(x2 + (size_t)3*16384*256, wihc_p, cbias, gic[1], 256, 768);
  cell_chunk<<<64, 512, 0, stream>>>(gic[0], whhc_p, bhh_c, hbuf, 32, hcT, out);
  cell_chunk<<<64, 512, 0, stream>>>(gic[1], whhc_p, bhh_c, hbuf, 48, hcT, out);

  v_out<<<16640, 256, 0, stream>>>(hcT, act, Wc, bc, out);
  attn_batch<<<1024, 256, 0, stream>>>(Ktl, hcT, wbv, Cm, p0, act, out);
}